// Round 2
// baseline (698.325 us; speedup 1.0000x reference)
//
#include <hip/hip_runtime.h>

#define NN 100000
#define EE 1600000
#define BB 256
#define IN_F 7
#define HH 128
#define NBKT 391        // ceil(NN/256) buckets for binned CSR fill
#define BIN_CHUNK 4096  // edges per bin_edges2 block

typedef unsigned int uint;
typedef unsigned short ushort;
typedef __attribute__((ext_vector_type(8))) short short8;
typedef __attribute__((ext_vector_type(4))) float f32x4;

// ---------------- bf16 helpers ----------------

__device__ __forceinline__ float bflo(uint u) { return __uint_as_float(u << 16); }
__device__ __forceinline__ float bfhi(uint u) { return __uint_as_float(u & 0xFFFF0000u); }
__device__ __forceinline__ ushort f2bf(float x) {   // RNE; inputs finite
    uint u = __float_as_uint(x);
    u = (u + 0x7FFFu + ((u >> 16) & 1u)) >> 16;
    return (ushort)u;
}

// ---------------- CSR build ----------------

__global__ void count_deg(const int* __restrict__ ei, int* __restrict__ deg, int e) {
    int i = blockIdx.x * 256 + threadIdx.x;
    if (i < e) atomicAdd(&deg[ei[e + i]], 1);   // dst = ei[E + i]
}

__global__ void scan_partial(const int* __restrict__ deg, int* __restrict__ bsum, int n) {
    __shared__ int sd[256];
    int b = blockIdx.x, t = threadIdx.x;
    int base = b * 1024 + t * 4;
    int s = 0;
    #pragma unroll
    for (int k = 0; k < 4; ++k) { int i = base + k; if (i < n) s += deg[i]; }
    sd[t] = s; __syncthreads();
    for (int off = 128; off > 0; off >>= 1) {
        if (t < off) sd[t] += sd[t + off];
        __syncthreads();
    }
    if (t == 0) bsum[b] = sd[0];
}

__global__ void scan_bsum(int* __restrict__ bsum, int nb) {
    __shared__ int sd[256];
    int t = threadIdx.x;
    int v = (t < nb) ? bsum[t] : 0;
    sd[t] = v; __syncthreads();
    for (int off = 1; off < 256; off <<= 1) {
        int add = (t >= off) ? sd[t - off] : 0;
        __syncthreads();
        sd[t] += add;
        __syncthreads();
    }
    if (t < nb) bsum[t] = sd[t] - v;   // exclusive
}

// also writes bcur[b] = rowptr[b*256] (init_bcur folded in)
__global__ void scan_apply(const int* __restrict__ deg, const int* __restrict__ bsum,
                           int* __restrict__ rowptr, int* __restrict__ bcur, int n, int e) {
    __shared__ int sd[256];
    int b = blockIdx.x, t = threadIdx.x;
    int base = b * 1024 + t * 4;
    int v[4]; int s = 0;
    #pragma unroll
    for (int k = 0; k < 4; ++k) { int i = base + k; v[k] = (i < n) ? deg[i] : 0; s += v[k]; }
    sd[t] = s; __syncthreads();
    int mine = s;
    for (int off = 1; off < 256; off <<= 1) {
        int add = (t >= off) ? sd[t - off] : 0;
        __syncthreads();
        sd[t] += add;
        __syncthreads();
    }
    int run = sd[t] - mine + bsum[b];
    #pragma unroll
    for (int k = 0; k < 4; ++k) {
        int i = base + k;
        if (i < n) {
            rowptr[i] = run;
            if ((i & 255) == 0) bcur[i >> 8] = run;
        }
        run += v[k];
    }
    if (b == 0 && t == 0) rowptr[n] = e;
}

// Pass A (two-level): per-block LDS histogram of the 391 buckets, one global
// atomicAdd per (block,bucket) to reserve a range, then LDS-cursor scatter.
// Packed entry: src (17b) | (dst&255) << 17.
__global__ __launch_bounds__(256) void bin_edges2(const int* __restrict__ ei,
        int* __restrict__ bcur, int* __restrict__ ebuf, int e) {
    __shared__ int hist[NBKT];
    __shared__ int base[NBKT];
    int t = threadIdx.x;
    int start = blockIdx.x * BIN_CHUNK;
    int end = start + BIN_CHUNK; if (end > e) end = e;
    for (int b = t; b < NBKT; b += 256) hist[b] = 0;
    __syncthreads();
    for (int i = start + t; i < end; i += 256)
        atomicAdd(&hist[ei[e + i] >> 8], 1);
    __syncthreads();
    for (int b = t; b < NBKT; b += 256) {
        int c = hist[b];
        base[b] = (c > 0) ? atomicAdd(&bcur[b], c) : 0;
        hist[b] = 0;
    }
    __syncthreads();
    for (int i = start + t; i < end; i += 256) {
        int d = ei[e + i], s = ei[i];
        int b = d >> 8;
        int pos = base[b] + atomicAdd(&hist[b], 1);
        ebuf[pos] = s | ((d & 255) << 17);
    }
}

// Pass B: one block per bucket; LDS cursors; colarr writes confined to the
// bucket's contiguous CSR region.
__global__ __launch_bounds__(256) void distribute(const int* __restrict__ ebuf,
        const int* __restrict__ rowptr, int* __restrict__ colarr, int n) {
    __shared__ int cur[256];
    int b = blockIdx.x, t = threadIdx.x;
    int n0 = b * 256;
    int n1 = n0 + 256; if (n1 > n) n1 = n;
    if (n0 + t < n1) cur[t] = rowptr[n0 + t];
    __syncthreads();
    int ebeg = rowptr[n0], eend = rowptr[n1];
    for (int i = ebeg + t; i < eend; i += 256) {
        int v = ebuf[i];
        int pos = atomicAdd(&cur[(v >> 17) & 255], 1);
        colarr[pos] = v & 0x1FFFF;
    }
}

// ---------------- weight pre-split (all 8 matrices, one launch) ----------------
// MFMA B-fragment layout: lane holds B[k=(lane>>4)*8+j][n=lane&15], j=0..7.
// Storage: [(kc*8+nt)*64 + lane]*8 + j. hi=bf16(W), lo=bf16(W-hi).

__global__ void wsplit_all(
        const float* __restrict__ w0, const float* __restrict__ w1,
        const float* __restrict__ w2, const float* __restrict__ w3,
        const float* __restrict__ w4, const float* __restrict__ w5,
        const float* __restrict__ w6, const float* __restrict__ w7,
        ushort* __restrict__ hiB, ushort* __restrict__ loB) {
    const float* ws[8] = {w0, w1, w2, w3, w4, w5, w6, w7};
    int gidx = blockIdx.x * 256 + threadIdx.x;   // 0..131071
    int mi = gidx >> 14;
    int idx = gidx & 16383;
    int j = idx & 7, l = (idx >> 3) & 63, blk = idx >> 9;
    int kc = blk >> 3, nt = blk & 7;
    int k = kc * 32 + (l >> 4) * 8 + j;
    int n = nt * 16 + (l & 15);
    float f = ws[mi][k * 128 + n];
    ushort h = f2bf(f);
    float hf = __uint_as_float((uint)h << 16);
    hiB[gidx] = h;
    loB[gidx] = f2bf(f - hf);
}

// ---------------- layer-0 aggregation (d=7) ----------------

__global__ __launch_bounds__(256) void agg7(const float* __restrict__ xin,
        const int* __restrict__ rowptr, const int* __restrict__ colarr,
        float* __restrict__ h0, int n) {
    int node = blockIdx.x * 32 + (threadIdx.x >> 3);
    int f = threadIdx.x & 7;
    if (node >= n) return;
    int fidx = (f < 7) ? f : 0;
    float acc = xin[node * 7 + fidx];
    int beg = rowptr[node], end = rowptr[node + 1];
    int j = beg;
    for (; j + 4 <= end; j += 4) {
        int s0 = colarr[j], s1 = colarr[j+1], s2 = colarr[j+2], s3 = colarr[j+3];
        float v0 = xin[s0*7 + fidx], v1 = xin[s1*7 + fidx];
        float v2 = xin[s2*7 + fidx], v3 = xin[s3*7 + fidx];
        acc += (v0 + v1) + (v2 + v3);
    }
    for (; j < end; ++j) acc += xin[colarr[j]*7 + fidx];
    h0[node * 8 + f] = (f < 7) ? acc : 0.f;
}

// ---------------- small first linear (bf16 output, row-major XB0) ----------------

__global__ __launch_bounds__(256) void lin7(const float* __restrict__ h0,
        const float* __restrict__ W, const float* __restrict__ bias,
        ushort* __restrict__ out, int n) {
    __shared__ float wl[7][128];
    __shared__ float hl[8][8];
    int t = threadIdx.x;
    for (int l = t; l < 7 * 128; l += 256) wl[l >> 7][l & 127] = W[l];
    int row0 = blockIdx.x * 8;
    if (t < 64) {
        int r = t >> 3, k = t & 7;
        int gr = row0 + r;
        hl[r][k] = (gr < n) ? h0[gr * 8 + k] : 0.f;
    }
    __syncthreads();
    int c = t & 127, g = t >> 7;
    float bv = bias[c];
    #pragma unroll
    for (int i = 0; i < 4; ++i) {
        int r = g * 4 + i, gr = row0 + r;
        if (gr < n) {
            float acc = bv;
            #pragma unroll
            for (int k = 0; k < 7; ++k) acc += hl[r][k] * wl[k][c];
            out[gr * 128 + c] = f2bf(fmaxf(acc, 0.f));
        }
    }
}

// ---------------- XCD-pinned sliced aggregation (R15) ----------------
// X stored as 8 planes [s][N][16] bf16 (3.2 MB/plane -> fits one XCD's 4 MB L2).
// Block (nb, s=blockIdx&7): consecutive blockIdx round-robin across the 8 XCDs,
// so slice s stays pinned to XCD s and its plane goes L2-resident. colarr and
// hbuf use non-temporal access to avoid evicting the plane.
// Output: hbuf[s][node][16] f32 = x_self + sum_nbr (slice cols).

__global__ __launch_bounds__(256, 8) void gather_slice(
        const ushort* __restrict__ xbs,   // [8][n][16] bf16 planes
        const int* __restrict__ rowptr, const int* __restrict__ colarr,
        float* __restrict__ hbuf, int n)  // [8][n][16] f32 planes
{
    __shared__ int idx[2048];
    int t = threadIdx.x;
    int s = blockIdx.x & 7;
    int nb = blockIdx.x >> 3;
    int row0 = nb * 64;
    const ushort* plane = xbs + (size_t)s * n * 16;
    float* hplane = hbuf + (size_t)s * n * 16;

    int rlast = row0 + 64; if (rlast > n) rlast = n;
    int eb = rowptr[row0];
    int cnt = rowptr[rlast] - eb;
    int staged = (cnt <= 2048) ? cnt : 0;   // all-or-nothing (cnt>2048 ~ never)
    for (int i = t; i < staged; i += 256)
        idx[i] = __builtin_nontemporal_load(&colarr[eb + i]);
    __syncthreads();

    int r = t >> 2, q = t & 3;              // 4 threads/row, 4 bf16 cols each
    int gr = row0 + r;
    if (gr >= n) return;
    uint2 sv = ((const uint2*)(plane + (size_t)gr * 16))[q];
    float a0 = bflo(sv.x), a1 = bfhi(sv.x), a2 = bflo(sv.y), a3 = bfhi(sv.y);
    int beg = rowptr[gr], end = rowptr[gr + 1];
    if (staged) {
        int j = beg - eb, je = end - eb;
        for (; j + 8 <= je; j += 8) {
            uint2 w0 = ((const uint2*)(plane + (size_t)idx[j + 0] * 16))[q];
            uint2 w1 = ((const uint2*)(plane + (size_t)idx[j + 1] * 16))[q];
            uint2 w2 = ((const uint2*)(plane + (size_t)idx[j + 2] * 16))[q];
            uint2 w3 = ((const uint2*)(plane + (size_t)idx[j + 3] * 16))[q];
            uint2 w4 = ((const uint2*)(plane + (size_t)idx[j + 4] * 16))[q];
            uint2 w5 = ((const uint2*)(plane + (size_t)idx[j + 5] * 16))[q];
            uint2 w6 = ((const uint2*)(plane + (size_t)idx[j + 6] * 16))[q];
            uint2 w7 = ((const uint2*)(plane + (size_t)idx[j + 7] * 16))[q];
            a0 += bflo(w0.x) + bflo(w1.x); a1 += bfhi(w0.x) + bfhi(w1.x);
            a2 += bflo(w0.y) + bflo(w1.y); a3 += bfhi(w0.y) + bfhi(w1.y);
            a0 += bflo(w2.x) + bflo(w3.x); a1 += bfhi(w2.x) + bfhi(w3.x);
            a2 += bflo(w2.y) + bflo(w3.y); a3 += bfhi(w2.y) + bfhi(w3.y);
            a0 += bflo(w4.x) + bflo(w5.x); a1 += bfhi(w4.x) + bfhi(w5.x);
            a2 += bflo(w4.y) + bflo(w5.y); a3 += bfhi(w4.y) + bfhi(w5.y);
            a0 += bflo(w6.x) + bflo(w7.x); a1 += bfhi(w6.x) + bfhi(w7.x);
            a2 += bflo(w6.y) + bflo(w7.y); a3 += bfhi(w6.y) + bfhi(w7.y);
        }
        for (; j < je; ++j) {
            uint2 w = ((const uint2*)(plane + (size_t)idx[j] * 16))[q];
            a0 += bflo(w.x); a1 += bfhi(w.x); a2 += bflo(w.y); a3 += bfhi(w.y);
        }
    } else {
        for (int j = beg; j < end; ++j) {
            int src = __builtin_nontemporal_load(&colarr[j]);
            uint2 w = ((const uint2*)(plane + (size_t)src * 16))[q];
            a0 += bflo(w.x); a1 += bfhi(w.x); a2 += bflo(w.y); a3 += bfhi(w.y);
        }
    }
    f32x4 o = (f32x4){a0, a1, a2, a3};
    __builtin_nontemporal_store(o, (f32x4*)&hplane[(size_t)gr * 16 + q * 4]);
}

// ------- MFMA MLP + JK + pool (256 thr = 4 waves); no gather inside -------

__device__ __forceinline__ int swz(int r) { return ((r >> 2) & 7) * 4; }

__device__ __forceinline__ void gemm_mfma(
        const ushort* __restrict__ WH, const ushort* __restrict__ WL,
        const float (&a_lds)[64][128], int mt, int lm, int lq, int l,
        f32x4 (&acc)[8])
{
    #pragma unroll
    for (int nt = 0; nt < 8; ++nt) acc[nt] = (f32x4){0.f, 0.f, 0.f, 0.f};
    const short8* BH = (const short8*)WH;
    const short8* BL = (const short8*)WL;
    int m = mt + lm;
    int s = swz(m);
    #pragma unroll
    for (int kc = 0; kc < 4; ++kc) {
        int cb = kc * 32 + lq * 8;
        float4 a0 = *(const float4*)&a_lds[m][cb ^ s];
        float4 a1 = *(const float4*)&a_lds[m][(cb + 4) ^ s];
        float av[8] = {a0.x, a0.y, a0.z, a0.w, a1.x, a1.y, a1.z, a1.w};
        short8 ah, al8;
        #pragma unroll
        for (int j = 0; j < 8; ++j) {
            ushort h = f2bf(av[j]);
            ah[j] = (short)h;
            float hf = __uint_as_float((uint)h << 16);
            al8[j] = (short)f2bf(av[j] - hf);
        }
        #pragma unroll
        for (int nt = 0; nt < 8; ++nt) {
            short8 bh = BH[(kc * 8 + nt) * 64 + l];
            short8 bl = BL[(kc * 8 + nt) * 64 + l];
            acc[nt] = __builtin_amdgcn_mfma_f32_16x16x32_bf16(ah,  bh, acc[nt], 0, 0, 0);
            acc[nt] = __builtin_amdgcn_mfma_f32_16x16x32_bf16(al8, bh, acc[nt], 0, 0, 0);
            acc[nt] = __builtin_amdgcn_mfma_f32_16x16x32_bf16(ah,  bl, acc[nt], 0, 0, 0);
        }
    }
}

// xout (when non-null) is written in SLICED layout [8][n][16] for gather_slice.
__device__ __forceinline__ void epi_store(f32x4 (&acc)[8], const float* __restrict__ bias,
        float (&a_lds)[64][128], int row0, int n, int mt, int lm, int lq,
        ushort* __restrict__ xout)
{
    #pragma unroll
    for (int nt = 0; nt < 8; ++nt) {
        int col = nt * 16 + lm;
        float bv = bias[col];
        #pragma unroll
        for (int r = 0; r < 4; ++r) {
            int row = mt + lq * 4 + r;
            int gr = row0 + row;
            float v = fmaxf(acc[nt][r] + bv, 0.f);
            if (gr >= n) v = 0.f;
            a_lds[row][col ^ swz(row)] = v;
            if (xout != nullptr && gr < n)
                xout[((size_t)nt * n + gr) * 16 + lm] = f2bf(v);
        }
    }
}

// INMODE 0: in = row-major bf16 [n][128] (layer-0 path, XB0)
// INMODE 1: in = f32 sliced planes [8][n][16] (hbuf from gather_slice)
template<int INMODE, bool DO_A, bool LASTB, bool WRITE_X>
__global__ __launch_bounds__(256) void mlp_fused(
        const void* __restrict__ in,
        const ushort* __restrict__ WaH, const ushort* __restrict__ WaL,
        const float* __restrict__ ba,
        const ushort* __restrict__ WbH, const ushort* __restrict__ WbL,
        const float* __restrict__ bb,
        const ushort* __restrict__ WjH, const ushort* __restrict__ WjL,
        const float* __restrict__ bjk,
        const int* __restrict__ batch,
        ushort* __restrict__ xout_bf, float* __restrict__ pooled, int n)
{
    __shared__ float a_lds[64][128];   // 32 KB
    int t = threadIdx.x;
    int row0 = blockIdx.x * 64;

    if (INMODE == 0) {
        // bf16 staging of t0: 1024 uint4 = 64 rows x 16 chunks
        const ushort* in_bf = (const ushort*)in;
        #pragma unroll
        for (int it = 0; it < 4; ++it) {
            int l = t + 256 * it;
            int r = l >> 4, c8 = (l & 15) * 8;
            int gr = row0 + r;
            uint4 v = make_uint4(0u, 0u, 0u, 0u);
            if (gr < n) v = *(const uint4*)&in_bf[(size_t)gr * 128 + c8];
            int s = swz(r);
            *(float4*)&a_lds[r][c8 ^ s] =
                make_float4(bflo(v.x), bfhi(v.x), bflo(v.y), bfhi(v.y));
            *(float4*)&a_lds[r][(c8 + 4) ^ s] =
                make_float4(bflo(v.z), bfhi(v.z), bflo(v.w), bfhi(v.w));
        }
    } else {
        // f32 sliced planes: 2048 float4 = 8 planes x 64 rows x 4 chunks
        const float* hb = (const float*)in;
        #pragma unroll
        for (int it = 0; it < 8; ++it) {
            int lin = it * 256 + t;
            int p = lin >> 8;
            int qq = lin & 255;
            int r = qq >> 2, c4 = (qq & 3) * 4;
            int gr = row0 + r;
            float4 v = make_float4(0.f, 0.f, 0.f, 0.f);
            if (gr < n) v = *(const float4*)&hb[((size_t)p * n + gr) * 16 + c4];
            *(float4*)&a_lds[r][(p * 16 + c4) ^ swz(r)] = v;
        }
    }
    __syncthreads();

    int w = t >> 6, l = t & 63;
    int mt = w * 16, lm = l & 15, lq = l >> 4;
    f32x4 acc[8];

    if (DO_A) {
        gemm_mfma(WaH, WaL, a_lds, mt, lm, lq, l, acc);
        __syncthreads();
        epi_store(acc, ba, a_lds, row0, n, mt, lm, lq, nullptr);
        __syncthreads();
    }

    gemm_mfma(WbH, WbL, a_lds, mt, lm, lq, l, acc);
    __syncthreads();
    epi_store(acc, bb, a_lds, row0, n, mt, lm, lq, WRITE_X ? xout_bf : nullptr);
    __syncthreads();

    gemm_mfma(WjH, WjL, a_lds, mt, lm, lq, l, acc);
    __syncthreads();

    // JK epilogue: +bjk (last layer), mask invalid rows, stage y into a_lds
    #pragma unroll
    for (int nt = 0; nt < 8; ++nt) {
        int col = nt * 16 + lm;
        float bv = LASTB ? bjk[col] : 0.f;
        #pragma unroll
        for (int r = 0; r < 4; ++r) {
            int row = mt + lq * 4 + r;
            int gr = row0 + row;
            float v = acc[nt][r] + bv;
            if (gr >= n) v = 0.f;
            a_lds[row][col ^ swz(row)] = v;
        }
    }
    __syncthreads();

    // pooling
    int row_last = row0 + 63; if (row_last > n - 1) row_last = n - 1;
    int g_first = batch[row0];
    int g_last  = batch[row_last];
    int c = t & 127, half = t >> 7;
    if (g_first == g_last) {
        float sacc = 0.f;
        for (int r = half * 32; r < half * 32 + 32; ++r)
            sacc += a_lds[r][c ^ swz(r)];
        __syncthreads();
        a_lds[half][c] = sacc;
        __syncthreads();
        if (t < 128)
            atomicAdd(&pooled[g_first * 128 + t], a_lds[0][t] + a_lds[1][t]);
    } else {
        float sacc = 0.f; int gprev = -1;
        for (int r = half * 32; r < half * 32 + 32; ++r) {
            int gr = row0 + r;
            if (gr >= n) break;
            int g = batch[gr];
            if (g != gprev) {
                if (gprev >= 0) atomicAdd(&pooled[gprev * 128 + c], sacc);
                sacc = 0.f; gprev = g;
            }
            sacc += a_lds[r][c ^ swz(r)];
        }
        if (gprev >= 0) atomicAdd(&pooled[gprev * 128 + c], sacc);
    }
}

// ---------------- classifier ----------------

__global__ __launch_bounds__(256) void classifier(const float* __restrict__ pooled,
        const float* __restrict__ Wc1, const float* __restrict__ bc1,
        const float* __restrict__ gamma, const float* __restrict__ beta,
        const float* __restrict__ rmean, const float* __restrict__ rvar,
        const float* __restrict__ Wc2, const float* __restrict__ bc2,
        float* __restrict__ out) {
    int g = blockIdx.x, t = threadIdx.x;
    __shared__ float p[128];
    __shared__ float r0[256], r1[256];
    if (t < 128) p[t] = pooled[g * 128 + t];
    __syncthreads();
    float acc = bc1[t];
    #pragma unroll 8
    for (int k = 0; k < 128; ++k) acc += p[k] * Wc1[k * 256 + t];
    float z = (acc - rmean[t]) * rsqrtf(rvar[t] + 1e-5f) * gamma[t] + beta[t];
    z = fmaxf(z, 0.f);
    r0[t] = z * Wc2[t * 2 + 0];
    r1[t] = z * Wc2[t * 2 + 1];
    __syncthreads();
    for (int s = 128; s > 0; s >>= 1) {
        if (t < s) { r0[t] += r0[t + s]; r1[t] += r1[t + s]; }
        __syncthreads();
    }
    if (t == 0) {
        out[g * 2 + 0] = r0[0] + bc2[0];
        out[g * 2 + 1] = r1[0] + bc2[1];
    }
}

// ---------------- launch ----------------

static inline size_t al256(size_t x) { return (x + 255) & ~size_t(255); }

extern "C" void kernel_launch(void* const* d_in, const int* in_sizes, int n_in,
                              void* d_out, int out_size, void* d_ws, size_t ws_size,
                              hipStream_t stream) {
    const float* x    = (const float*)d_in[0];
    const int*   ei   = (const int*)  d_in[1];
    const int*   batch= (const int*)  d_in[3];
    const float* W0a = (const float*)d_in[4];  const float* b0a = (const float*)d_in[5];
    const float* W0b = (const float*)d_in[6];  const float* b0b = (const float*)d_in[7];
    const float* W1a = (const float*)d_in[8];  const float* b1a = (const float*)d_in[9];
    const float* W1b = (const float*)d_in[10]; const float* b1b = (const float*)d_in[11];
    const float* W2a = (const float*)d_in[12]; const float* b2a = (const float*)d_in[13];
    const float* W2b = (const float*)d_in[14]; const float* b2b = (const float*)d_in[15];
    const float* Wjk = (const float*)d_in[16]; const float* bjk = (const float*)d_in[17];
    const float* Wc1 = (const float*)d_in[18]; const float* bc1 = (const float*)d_in[19];
    const float* gamma=(const float*)d_in[20]; const float* beta= (const float*)d_in[21];
    const float* rmean=(const float*)d_in[22]; const float* rvar= (const float*)d_in[23];
    const float* Wc2 = (const float*)d_in[24]; const float* bc2 = (const float*)d_in[25];
    float* out = (float*)d_out;

    const int N = NN, E = EE, B = BB;

    char* w = (char*)d_ws;
    size_t off = 0;
    int* deg    = (int*)(w + off); off = al256(off + (size_t)N * 4);
    int* rowptr = (int*)(w + off); off = al256(off + (size_t)(N + 1) * 4);
    int* bcur   = (int*)(w + off); off = al256(off + (size_t)NBKT * 4);
    int* colarr = (int*)(w + off); off = al256(off + (size_t)E * 4);
    int* ebuf   = (int*)(w + off); off = al256(off + (size_t)E * 4);
    int* bsum   = (int*)(w + off); off = al256(off + 1024 * 4);
    float* h0   = (float*)(w + off); off = al256(off + (size_t)N * 8 * 4);
    ushort* XB0 = (ushort*)(w + off); off = al256(off + (size_t)N * 128 * 2);   // row-major
    ushort* XB1s= (ushort*)(w + off); off = al256(off + (size_t)N * 128 * 2);   // sliced [8][N][16]
    ushort* XB2s= (ushort*)(w + off); off = al256(off + (size_t)N * 128 * 2);   // sliced [8][N][16]
    float* pooled = (float*)(w + off); off = al256(off + (size_t)B * 128 * 4);
    ushort* wfH = (ushort*)(w + off); off = al256(off + (size_t)8 * 16384 * 2);
    ushort* wfL = (ushort*)(w + off); off = al256(off + (size_t)8 * 16384 * 2);
    float* hbuf = (float*)(w + off); off = al256(off + (size_t)N * 128 * 4);    // sliced f32 [8][N][16]

    hipMemsetAsync(deg, 0, (size_t)N * 4, stream);
    hipMemsetAsync(pooled, 0, (size_t)B * 128 * 4, stream);

    // pre-split weights (order: W0b, W1a, W1b, W2a, W2b, Wjk0, Wjk1, Wjk2)
    wsplit_all<<<512, 256, 0, stream>>>(W0b, W1a, W1b, W2a, W2b,
                                        Wjk, Wjk + 128 * 128, Wjk + 256 * 128,
                                        wfH, wfL);

    int nb = (N + 1023) / 1024;   // 98

    count_deg<<<(E + 255) / 256, 256, 0, stream>>>(ei, deg, E);
    scan_partial<<<nb, 256, 0, stream>>>(deg, bsum, N);
    scan_bsum<<<1, 256, 0, stream>>>(bsum, nb);
    scan_apply<<<nb, 256, 0, stream>>>(deg, bsum, rowptr, bcur, N, E);
    bin_edges2<<<(E + BIN_CHUNK - 1) / BIN_CHUNK, 256, 0, stream>>>(ei, bcur, ebuf, E);
    distribute<<<NBKT, 256, 0, stream>>>(ebuf, rowptr, colarr, N);

    int gLin = (N + 63) / 64;   // 1563

    // Layer 0: agg7 -> lin7 (bf16 t0 -> XB0 row-major) -> mlp0, x1 -> XB1s (sliced)
    agg7<<<(N + 31) / 32, 256, 0, stream>>>(x, rowptr, colarr, h0, N);
    lin7<<<(N + 7) / 8, 256, 0, stream>>>(h0, W0a, b0a, XB0, N);
    mlp_fused<0, false, false, true><<<gLin, 256, 0, stream>>>(
        XB0,
        nullptr, nullptr, nullptr,
        wfH + 0 * 16384, wfL + 0 * 16384, b0b,
        wfH + 5 * 16384, wfL + 5 * 16384, nullptr,
        batch, XB1s, pooled, N);

    // Layer 1: XCD-sliced gather XB1s -> hbuf; MLP -> x2 -> XB2s (sliced)
    gather_slice<<<gLin * 8, 256, 0, stream>>>(XB1s, rowptr, colarr, hbuf, N);
    mlp_fused<1, true, false, true><<<gLin, 256, 0, stream>>>(
        hbuf,
        wfH + 1 * 16384, wfL + 1 * 16384, b1a,
        wfH + 2 * 16384, wfL + 2 * 16384, b1b,
        wfH + 6 * 16384, wfL + 6 * 16384, nullptr,
        batch, XB2s, pooled, N);

    // Layer 2: XCD-sliced gather XB2s -> hbuf; MLP -> jk2 (x3 never materialized)
    gather_slice<<<gLin * 8, 256, 0, stream>>>(XB2s, rowptr, colarr, hbuf, N);
    mlp_fused<1, true, true, false><<<gLin, 256, 0, stream>>>(
        hbuf,
        wfH + 3 * 16384, wfL + 3 * 16384, b2a,
        wfH + 4 * 16384, wfL + 4 * 16384, b2b,
        wfH + 7 * 16384, wfL + 7 * 16384, bjk,
        batch, nullptr, pooled, N);

    classifier<<<B, 256, 0, stream>>>(pooled, Wc1, bc1, gamma, beta,
                                      rmean, rvar, Wc2, bc2, out);
}

// Round 3
// 508.112 us; speedup vs baseline: 1.3744x; 1.3744x over previous
//
#include <hip/hip_runtime.h>

#define NN 100000
#define EE 1600000
#define BB 256
#define IN_F 7
#define HH 128
#define NBKT 391        // ceil(NN/256) buckets for binned CSR fill
#define BIN_CHUNK 4096  // edges per bin_edges2 block

typedef unsigned int uint;
typedef unsigned short ushort;
typedef __attribute__((ext_vector_type(8))) short short8;
typedef __attribute__((ext_vector_type(4))) float f32x4;

// ---------------- bf16 helpers ----------------

__device__ __forceinline__ float bflo(uint u) { return __uint_as_float(u << 16); }
__device__ __forceinline__ float bfhi(uint u) { return __uint_as_float(u & 0xFFFF0000u); }
__device__ __forceinline__ ushort f2bf(float x) {   // RNE; inputs finite
    uint u = __float_as_uint(x);
    u = (u + 0x7FFFu + ((u >> 16) & 1u)) >> 16;
    return (ushort)u;
}

// ---------------- CSR build ----------------

__global__ void count_deg(const int* __restrict__ ei, int* __restrict__ deg, int e) {
    int i = blockIdx.x * 256 + threadIdx.x;
    if (i < e) atomicAdd(&deg[ei[e + i]], 1);   // dst = ei[E + i]
}

__global__ void scan_partial(const int* __restrict__ deg, int* __restrict__ bsum, int n) {
    __shared__ int sd[256];
    int b = blockIdx.x, t = threadIdx.x;
    int base = b * 1024 + t * 4;
    int s = 0;
    #pragma unroll
    for (int k = 0; k < 4; ++k) { int i = base + k; if (i < n) s += deg[i]; }
    sd[t] = s; __syncthreads();
    for (int off = 128; off > 0; off >>= 1) {
        if (t < off) sd[t] += sd[t + off];
        __syncthreads();
    }
    if (t == 0) bsum[b] = sd[0];
}

__global__ void scan_bsum(int* __restrict__ bsum, int nb) {
    __shared__ int sd[256];
    int t = threadIdx.x;
    int v = (t < nb) ? bsum[t] : 0;
    sd[t] = v; __syncthreads();
    for (int off = 1; off < 256; off <<= 1) {
        int add = (t >= off) ? sd[t - off] : 0;
        __syncthreads();
        sd[t] += add;
        __syncthreads();
    }
    if (t < nb) bsum[t] = sd[t] - v;   // exclusive
}

// also writes bcur[b] = rowptr[b*256] (init_bcur folded in)
__global__ void scan_apply(const int* __restrict__ deg, const int* __restrict__ bsum,
                           int* __restrict__ rowptr, int* __restrict__ bcur, int n, int e) {
    __shared__ int sd[256];
    int b = blockIdx.x, t = threadIdx.x;
    int base = b * 1024 + t * 4;
    int v[4]; int s = 0;
    #pragma unroll
    for (int k = 0; k < 4; ++k) { int i = base + k; v[k] = (i < n) ? deg[i] : 0; s += v[k]; }
    sd[t] = s; __syncthreads();
    int mine = s;
    for (int off = 1; off < 256; off <<= 1) {
        int add = (t >= off) ? sd[t - off] : 0;
        __syncthreads();
        sd[t] += add;
        __syncthreads();
    }
    int run = sd[t] - mine + bsum[b];
    #pragma unroll
    for (int k = 0; k < 4; ++k) {
        int i = base + k;
        if (i < n) {
            rowptr[i] = run;
            if ((i & 255) == 0) bcur[i >> 8] = run;
        }
        run += v[k];
    }
    if (b == 0 && t == 0) rowptr[n] = e;
}

// Pass A (two-level): per-block LDS histogram of the 391 buckets, one global
// atomicAdd per (block,bucket) to reserve a range, then LDS-cursor scatter.
// Packed entry: src (17b) | (dst&255) << 17.
__global__ __launch_bounds__(256) void bin_edges2(const int* __restrict__ ei,
        int* __restrict__ bcur, int* __restrict__ ebuf, int e) {
    __shared__ int hist[NBKT];
    __shared__ int base[NBKT];
    int t = threadIdx.x;
    int start = blockIdx.x * BIN_CHUNK;
    int end = start + BIN_CHUNK; if (end > e) end = e;
    for (int b = t; b < NBKT; b += 256) hist[b] = 0;
    __syncthreads();
    for (int i = start + t; i < end; i += 256)
        atomicAdd(&hist[ei[e + i] >> 8], 1);
    __syncthreads();
    for (int b = t; b < NBKT; b += 256) {
        int c = hist[b];
        base[b] = (c > 0) ? atomicAdd(&bcur[b], c) : 0;
        hist[b] = 0;
    }
    __syncthreads();
    for (int i = start + t; i < end; i += 256) {
        int d = ei[e + i], s = ei[i];
        int b = d >> 8;
        int pos = base[b] + atomicAdd(&hist[b], 1);
        ebuf[pos] = s | ((d & 255) << 17);
    }
}

// Pass B: one block per bucket; LDS cursors; colarr writes confined to the
// bucket's contiguous CSR region.
__global__ __launch_bounds__(256) void distribute(const int* __restrict__ ebuf,
        const int* __restrict__ rowptr, int* __restrict__ colarr, int n) {
    __shared__ int cur[256];
    int b = blockIdx.x, t = threadIdx.x;
    int n0 = b * 256;
    int n1 = n0 + 256; if (n1 > n) n1 = n;
    if (n0 + t < n1) cur[t] = rowptr[n0 + t];
    __syncthreads();
    int ebeg = rowptr[n0], eend = rowptr[n1];
    for (int i = ebeg + t; i < eend; i += 256) {
        int v = ebuf[i];
        int pos = atomicAdd(&cur[(v >> 17) & 255], 1);
        colarr[pos] = v & 0x1FFFF;
    }
}

// ---------------- weight pre-split (all 8 matrices, one launch) ----------------
// MFMA B-fragment layout: lane holds B[k=(lane>>4)*8+j][n=lane&15], j=0..7.
// Storage: [(kc*8+nt)*64 + lane]*8 + j. hi=bf16(W), lo=bf16(W-hi).

__global__ void wsplit_all(
        const float* __restrict__ w0, const float* __restrict__ w1,
        const float* __restrict__ w2, const float* __restrict__ w3,
        const float* __restrict__ w4, const float* __restrict__ w5,
        const float* __restrict__ w6, const float* __restrict__ w7,
        ushort* __restrict__ hiB, ushort* __restrict__ loB) {
    const float* ws[8] = {w0, w1, w2, w3, w4, w5, w6, w7};
    int gidx = blockIdx.x * 256 + threadIdx.x;   // 0..131071
    int mi = gidx >> 14;
    int idx = gidx & 16383;
    int j = idx & 7, l = (idx >> 3) & 63, blk = idx >> 9;
    int kc = blk >> 3, nt = blk & 7;
    int k = kc * 32 + (l >> 4) * 8 + j;
    int n = nt * 16 + (l & 15);
    float f = ws[mi][k * 128 + n];
    ushort h = f2bf(f);
    float hf = __uint_as_float((uint)h << 16);
    hiB[gidx] = h;
    loB[gidx] = f2bf(f - hf);
}

// ---------------- layer-0 aggregation (d=7) ----------------

__global__ __launch_bounds__(256) void agg7(const float* __restrict__ xin,
        const int* __restrict__ rowptr, const int* __restrict__ colarr,
        float* __restrict__ h0, int n) {
    int node = blockIdx.x * 32 + (threadIdx.x >> 3);
    int f = threadIdx.x & 7;
    if (node >= n) return;
    int fidx = (f < 7) ? f : 0;
    float acc = xin[node * 7 + fidx];
    int beg = rowptr[node], end = rowptr[node + 1];
    int j = beg;
    for (; j + 4 <= end; j += 4) {
        int s0 = colarr[j], s1 = colarr[j+1], s2 = colarr[j+2], s3 = colarr[j+3];
        float v0 = xin[s0*7 + fidx], v1 = xin[s1*7 + fidx];
        float v2 = xin[s2*7 + fidx], v3 = xin[s3*7 + fidx];
        acc += (v0 + v1) + (v2 + v3);
    }
    for (; j < end; ++j) acc += xin[colarr[j]*7 + fidx];
    h0[node * 8 + f] = (f < 7) ? acc : 0.f;
}

// ---------------- small first linear (bf16 output, row-major XB0) ----------------

__global__ __launch_bounds__(256) void lin7(const float* __restrict__ h0,
        const float* __restrict__ W, const float* __restrict__ bias,
        ushort* __restrict__ out, int n) {
    __shared__ float wl[7][128];
    __shared__ float hl[8][8];
    int t = threadIdx.x;
    for (int l = t; l < 7 * 128; l += 256) wl[l >> 7][l & 127] = W[l];
    int row0 = blockIdx.x * 8;
    if (t < 64) {
        int r = t >> 3, k = t & 7;
        int gr = row0 + r;
        hl[r][k] = (gr < n) ? h0[gr * 8 + k] : 0.f;
    }
    __syncthreads();
    int c = t & 127, g = t >> 7;
    float bv = bias[c];
    #pragma unroll
    for (int i = 0; i < 4; ++i) {
        int r = g * 4 + i, gr = row0 + r;
        if (gr < n) {
            float acc = bv;
            #pragma unroll
            for (int k = 0; k < 7; ++k) acc += hl[r][k] * wl[k][c];
            out[gr * 128 + c] = f2bf(fmaxf(acc, 0.f));
        }
    }
}

// ------- fused [bf16 gather] + MFMA MLP + JK + pool (256 thr = 4 waves) -------
// R16: LDS holds A as bf16 hi/lo (split once at write time; ds_read_b128 feeds
// MFMA directly, zero cvt in the GEMM loop). Each wave owns 2 of 8 nt column
// tiles (acc[4 mt][2 nt]) -> per-gemm weight-fragment reads drop 4x (L2 BW).

// element (r, cu) lives at bufHL[h][r][ ((cu>>3) ^ (r&7))*8 + (cu&7) ]
__device__ __forceinline__ int swch(int chunk, int r) { return chunk ^ (r & 7); }

__device__ __forceinline__ void gemm_mfma(
        const ushort* __restrict__ WH, const ushort* __restrict__ WL,
        const ushort (&bufHL)[2][64][128], int w, int lm, int lq, int l,
        f32x4 (&acc)[4][2])
{
    #pragma unroll
    for (int mi = 0; mi < 4; ++mi)
        #pragma unroll
        for (int nj = 0; nj < 2; ++nj) acc[mi][nj] = (f32x4){0.f, 0.f, 0.f, 0.f};
    const short8* BH = (const short8*)WH;
    const short8* BL = (const short8*)WL;
    #pragma unroll
    for (int kc = 0; kc < 4; ++kc) {
        short8 bh0 = BH[(kc * 8 + 2 * w + 0) * 64 + l];
        short8 bl0 = BL[(kc * 8 + 2 * w + 0) * 64 + l];
        short8 bh1 = BH[(kc * 8 + 2 * w + 1) * 64 + l];
        short8 bl1 = BL[(kc * 8 + 2 * w + 1) * 64 + l];
        #pragma unroll
        for (int mi = 0; mi < 4; ++mi) {
            int row = mi * 16 + lm;
            int ch = swch(kc * 4 + lq, row);
            short8 ah = *(const short8*)&bufHL[0][row][ch * 8];
            short8 al = *(const short8*)&bufHL[1][row][ch * 8];
            acc[mi][0] = __builtin_amdgcn_mfma_f32_16x16x32_bf16(ah, bh0, acc[mi][0], 0, 0, 0);
            acc[mi][0] = __builtin_amdgcn_mfma_f32_16x16x32_bf16(al, bh0, acc[mi][0], 0, 0, 0);
            acc[mi][0] = __builtin_amdgcn_mfma_f32_16x16x32_bf16(ah, bl0, acc[mi][0], 0, 0, 0);
            acc[mi][1] = __builtin_amdgcn_mfma_f32_16x16x32_bf16(ah, bh1, acc[mi][1], 0, 0, 0);
            acc[mi][1] = __builtin_amdgcn_mfma_f32_16x16x32_bf16(al, bh1, acc[mi][1], 0, 0, 0);
            acc[mi][1] = __builtin_amdgcn_mfma_f32_16x16x32_bf16(ah, bl1, acc[mi][1], 0, 0, 0);
        }
    }
}

// relu + bias; write hi/lo back to LDS; optional row-major bf16 XB out
__device__ __forceinline__ void epi_store(f32x4 (&acc)[4][2], const float* __restrict__ bias,
        ushort (&bufHL)[2][64][128], int row0, int n, int w, int lm, int lq,
        ushort* __restrict__ xout)
{
    #pragma unroll
    for (int nj = 0; nj < 2; ++nj) {
        int col = (2 * w + nj) * 16 + lm;
        float bv = bias[col];
        #pragma unroll
        for (int mi = 0; mi < 4; ++mi) {
            #pragma unroll
            for (int rr = 0; rr < 4; ++rr) {
                int row = mi * 16 + lq * 4 + rr;
                int gr = row0 + row;
                float v = fmaxf(acc[mi][nj][rr] + bv, 0.f);
                if (gr >= n) v = 0.f;
                ushort hi = f2bf(v);
                float hf = __uint_as_float((uint)hi << 16);
                ushort lo = f2bf(v - hf);
                int off = (swch(col >> 3, row) << 3) | (col & 7);
                bufHL[0][row][off] = hi;
                bufHL[1][row][off] = lo;
                if (xout != nullptr && gr < n)
                    xout[(size_t)gr * 128 + col] = hi;
            }
        }
    }
}

template<bool GATHER, bool DO_A, bool LASTB, bool WRITE_X>
__global__ __launch_bounds__(256) void mlp_fused(
        const ushort* __restrict__ in_bf,
        const int* __restrict__ rowptr, const int* __restrict__ colarr,
        const ushort* __restrict__ WaH, const ushort* __restrict__ WaL,
        const float* __restrict__ ba,
        const ushort* __restrict__ WbH, const ushort* __restrict__ WbL,
        const float* __restrict__ bb,
        const ushort* __restrict__ WjH, const ushort* __restrict__ WjL,
        const float* __restrict__ bjk,
        const int* __restrict__ batch,
        ushort* __restrict__ xout_bf, float* __restrict__ pooled, int n)
{
    __shared__ __align__(16) ushort bufHL[2][64][128];   // 32 KB (hi | lo)
    int t = threadIdx.x;
    int row0 = blockIdx.x * 64;

    if (GATHER) {
        // R12 gather: LDS-staged indices, accumulate f32 in regs, split at write.
        int* idx_lds = (int*)&bufHL[0][0][0];      // capacity 8192 ints (32 KB)
        int rlast = row0 + 64; if (rlast > n) rlast = n;
        int eb = rowptr[row0];
        int cnt = rowptr[rlast] - eb;
        int staged = cnt < 8192 ? cnt : 8192;
        for (int i = t; i < staged; i += 256) idx_lds[i] = colarr[eb + i];
        __syncthreads();

        int r = t >> 2, q = t & 3;
        int gr = row0 + r;
        float f[4][8];
        #pragma unroll
        for (int i = 0; i < 4; ++i)
            #pragma unroll
            for (int j = 0; j < 8; ++j) f[i][j] = 0.f;
        if (gr < n) {
            const uint4* sp = (const uint4*)(in_bf + (size_t)gr * 128);
            #pragma unroll
            for (int i = 0; i < 4; ++i) {
                uint4 v = sp[i * 4 + q];
                f[i][0] = bflo(v.x); f[i][1] = bfhi(v.x);
                f[i][2] = bflo(v.y); f[i][3] = bfhi(v.y);
                f[i][4] = bflo(v.z); f[i][5] = bfhi(v.z);
                f[i][6] = bflo(v.w); f[i][7] = bfhi(v.w);
            }
            int beg = rowptr[gr] - eb, end = rowptr[gr + 1] - eb;
            int j = beg;
            for (; j + 2 <= end; j += 2) {
                int s0 = (j     < staged) ? idx_lds[j]     : colarr[eb + j];
                int s1 = (j + 1 < staged) ? idx_lds[j + 1] : colarr[eb + j + 1];
                const uint4* n0 = (const uint4*)(in_bf + (size_t)s0 * 128);
                const uint4* n1 = (const uint4*)(in_bf + (size_t)s1 * 128);
                uint4 v0[4], v1[4];
                #pragma unroll
                for (int i = 0; i < 4; ++i) { v0[i] = n0[i * 4 + q]; v1[i] = n1[i * 4 + q]; }
                #pragma unroll
                for (int i = 0; i < 4; ++i) {
                    f[i][0] += bflo(v0[i].x) + bflo(v1[i].x);
                    f[i][1] += bfhi(v0[i].x) + bfhi(v1[i].x);
                    f[i][2] += bflo(v0[i].y) + bflo(v1[i].y);
                    f[i][3] += bfhi(v0[i].y) + bfhi(v1[i].y);
                    f[i][4] += bflo(v0[i].z) + bflo(v1[i].z);
                    f[i][5] += bfhi(v0[i].z) + bfhi(v1[i].z);
                    f[i][6] += bflo(v0[i].w) + bflo(v1[i].w);
                    f[i][7] += bfhi(v0[i].w) + bfhi(v1[i].w);
                }
            }
            for (; j < end; ++j) {
                int s0 = (j < staged) ? idx_lds[j] : colarr[eb + j];
                const uint4* np = (const uint4*)(in_bf + (size_t)s0 * 128);
                #pragma unroll
                for (int i = 0; i < 4; ++i) {
                    uint4 v = np[i * 4 + q];
                    f[i][0] += bflo(v.x); f[i][1] += bfhi(v.x);
                    f[i][2] += bflo(v.y); f[i][3] += bfhi(v.y);
                    f[i][4] += bflo(v.z); f[i][5] += bfhi(v.z);
                    f[i][6] += bflo(v.w); f[i][7] += bfhi(v.w);
                }
            }
        }
        __syncthreads();   // all idx_lds reads done before bufHL is overwritten
        #pragma unroll
        for (int i = 0; i < 4; ++i) {
            short8 hi8, lo8;
            #pragma unroll
            for (int j = 0; j < 8; ++j) {
                ushort h = f2bf(f[i][j]);
                hi8[j] = (short)h;
                float hf = __uint_as_float((uint)h << 16);
                lo8[j] = (short)f2bf(f[i][j] - hf);
            }
            int ch = swch(i * 4 + q, r);
            *(short8*)&bufHL[0][r][ch * 8] = hi8;
            *(short8*)&bufHL[1][r][ch * 8] = lo8;
        }
    } else {
        // bf16 staging of t0: hi = input (already bf16), lo = 0
        #pragma unroll
        for (int it = 0; it < 4; ++it) {
            int l = t + 256 * it;
            int r = l >> 4, c = l & 15;
            int gr = row0 + r;
            uint4 v = make_uint4(0u, 0u, 0u, 0u);
            if (gr < n) v = *(const uint4*)&in_bf[(size_t)gr * 128 + c * 8];
            int ch = swch(c, r);
            *(uint4*)&bufHL[0][r][ch * 8] = v;
            *(uint4*)&bufHL[1][r][ch * 8] = make_uint4(0u, 0u, 0u, 0u);
        }
    }
    __syncthreads();

    int w = t >> 6, l = t & 63;
    int lm = l & 15, lq = l >> 4;
    f32x4 acc[4][2];

    if (DO_A) {
        gemm_mfma(WaH, WaL, bufHL, w, lm, lq, l, acc);
        __syncthreads();
        epi_store(acc, ba, bufHL, row0, n, w, lm, lq, nullptr);
        __syncthreads();
    }

    gemm_mfma(WbH, WbL, bufHL, w, lm, lq, l, acc);
    __syncthreads();
    epi_store(acc, bb, bufHL, row0, n, w, lm, lq, WRITE_X ? xout_bf : nullptr);
    __syncthreads();

    gemm_mfma(WjH, WjL, bufHL, w, lm, lq, l, acc);
    __syncthreads();

    // JK epilogue: +bjk (last layer), mask invalid rows, stage hi/lo into LDS
    #pragma unroll
    for (int nj = 0; nj < 2; ++nj) {
        int col = (2 * w + nj) * 16 + lm;
        float bv = LASTB ? bjk[col] : 0.f;
        #pragma unroll
        for (int mi = 0; mi < 4; ++mi) {
            #pragma unroll
            for (int rr = 0; rr < 4; ++rr) {
                int row = mi * 16 + lq * 4 + rr;
                int gr = row0 + row;
                float v = acc[mi][nj][rr] + bv;
                if (gr >= n) v = 0.f;
                ushort hi = f2bf(v);
                float hf = __uint_as_float((uint)hi << 16);
                ushort lo = f2bf(v - hf);
                int off = (swch(col >> 3, row) << 3) | (col & 7);
                bufHL[0][row][off] = hi;
                bufHL[1][row][off] = lo;
            }
        }
    }
    __syncthreads();

    // pooling (values decoded as hi+lo; ~2^-17 rel error, negligible)
    int row_last = row0 + 63; if (row_last > n - 1) row_last = n - 1;
    int g_first = batch[row0];
    int g_last  = batch[row_last];
    int c = t & 127, half = t >> 7;
    if (g_first == g_last) {
        float sacc = 0.f;
        #pragma unroll 4
        for (int r = half * 32; r < half * 32 + 32; ++r) {
            int off = (swch(c >> 3, r) << 3) | (c & 7);
            sacc += __uint_as_float((uint)bufHL[0][r][off] << 16)
                  + __uint_as_float((uint)bufHL[1][r][off] << 16);
        }
        __syncthreads();
        float* scr = (float*)&bufHL[0][0][0];   // 256 floats scratch
        scr[t] = sacc;
        __syncthreads();
        if (t < 128)
            atomicAdd(&pooled[g_first * 128 + t], scr[t] + scr[t + 128]);
    } else {
        float sacc = 0.f; int gprev = -1;
        for (int r = half * 32; r < half * 32 + 32; ++r) {
            int gr = row0 + r;
            if (gr >= n) break;
            int g = batch[gr];
            if (g != gprev) {
                if (gprev >= 0) atomicAdd(&pooled[gprev * 128 + c], sacc);
                sacc = 0.f; gprev = g;
            }
            int off = (swch(c >> 3, r) << 3) | (c & 7);
            sacc += __uint_as_float((uint)bufHL[0][r][off] << 16)
                  + __uint_as_float((uint)bufHL[1][r][off] << 16);
        }
        if (gprev >= 0) atomicAdd(&pooled[gprev * 128 + c], sacc);
    }
}

// ---------------- classifier ----------------

__global__ __launch_bounds__(256) void classifier(const float* __restrict__ pooled,
        const float* __restrict__ Wc1, const float* __restrict__ bc1,
        const float* __restrict__ gamma, const float* __restrict__ beta,
        const float* __restrict__ rmean, const float* __restrict__ rvar,
        const float* __restrict__ Wc2, const float* __restrict__ bc2,
        float* __restrict__ out) {
    int g = blockIdx.x, t = threadIdx.x;
    __shared__ float p[128];
    __shared__ float r0[256], r1[256];
    if (t < 128) p[t] = pooled[g * 128 + t];
    __syncthreads();
    float acc = bc1[t];
    #pragma unroll 8
    for (int k = 0; k < 128; ++k) acc += p[k] * Wc1[k * 256 + t];
    float z = (acc - rmean[t]) * rsqrtf(rvar[t] + 1e-5f) * gamma[t] + beta[t];
    z = fmaxf(z, 0.f);
    r0[t] = z * Wc2[t * 2 + 0];
    r1[t] = z * Wc2[t * 2 + 1];
    __syncthreads();
    for (int s = 128; s > 0; s >>= 1) {
        if (t < s) { r0[t] += r0[t + s]; r1[t] += r1[t + s]; }
        __syncthreads();
    }
    if (t == 0) {
        out[g * 2 + 0] = r0[0] + bc2[0];
        out[g * 2 + 1] = r1[0] + bc2[1];
    }
}

// ---------------- launch ----------------

static inline size_t al256(size_t x) { return (x + 255) & ~size_t(255); }

extern "C" void kernel_launch(void* const* d_in, const int* in_sizes, int n_in,
                              void* d_out, int out_size, void* d_ws, size_t ws_size,
                              hipStream_t stream) {
    const float* x    = (const float*)d_in[0];
    const int*   ei   = (const int*)  d_in[1];
    const int*   batch= (const int*)  d_in[3];
    const float* W0a = (const float*)d_in[4];  const float* b0a = (const float*)d_in[5];
    const float* W0b = (const float*)d_in[6];  const float* b0b = (const float*)d_in[7];
    const float* W1a = (const float*)d_in[8];  const float* b1a = (const float*)d_in[9];
    const float* W1b = (const float*)d_in[10]; const float* b1b = (const float*)d_in[11];
    const float* W2a = (const float*)d_in[12]; const float* b2a = (const float*)d_in[13];
    const float* W2b = (const float*)d_in[14]; const float* b2b = (const float*)d_in[15];
    const float* Wjk = (const float*)d_in[16]; const float* bjk = (const float*)d_in[17];
    const float* Wc1 = (const float*)d_in[18]; const float* bc1 = (const float*)d_in[19];
    const float* gamma=(const float*)d_in[20]; const float* beta= (const float*)d_in[21];
    const float* rmean=(const float*)d_in[22]; const float* rvar= (const float*)d_in[23];
    const float* Wc2 = (const float*)d_in[24]; const float* bc2 = (const float*)d_in[25];
    float* out = (float*)d_out;

    const int N = NN, E = EE, B = BB;

    char* w = (char*)d_ws;
    size_t off = 0;
    int* deg    = (int*)(w + off); off = al256(off + (size_t)N * 4);
    int* rowptr = (int*)(w + off); off = al256(off + (size_t)(N + 1) * 4);
    int* bcur   = (int*)(w + off); off = al256(off + (size_t)NBKT * 4);
    int* colarr = (int*)(w + off); off = al256(off + (size_t)E * 4);
    int* ebuf   = (int*)(w + off); off = al256(off + (size_t)E * 4);
    int* bsum   = (int*)(w + off); off = al256(off + 1024 * 4);
    float* h0   = (float*)(w + off); off = al256(off + (size_t)N * 8 * 4);
    ushort* XB0 = (ushort*)(w + off); off = al256(off + (size_t)N * 128 * 2);
    ushort* XB1 = (ushort*)(w + off); off = al256(off + (size_t)N * 128 * 2);
    ushort* XB2 = (ushort*)(w + off); off = al256(off + (size_t)N * 128 * 2);
    float* pooled = (float*)(w + off); off = al256(off + (size_t)B * 128 * 4);
    ushort* wfH = (ushort*)(w + off); off = al256(off + (size_t)8 * 16384 * 2);
    ushort* wfL = (ushort*)(w + off); off = al256(off + (size_t)8 * 16384 * 2);

    hipMemsetAsync(deg, 0, (size_t)N * 4, stream);
    hipMemsetAsync(pooled, 0, (size_t)B * 128 * 4, stream);

    // pre-split weights (order: W0b, W1a, W1b, W2a, W2b, Wjk0, Wjk1, Wjk2)
    wsplit_all<<<512, 256, 0, stream>>>(W0b, W1a, W1b, W2a, W2b,
                                        Wjk, Wjk + 128 * 128, Wjk + 256 * 128,
                                        wfH, wfL);

    int nb = (N + 1023) / 1024;   // 98

    count_deg<<<(E + 255) / 256, 256, 0, stream>>>(ei, deg, E);
    scan_partial<<<nb, 256, 0, stream>>>(deg, bsum, N);
    scan_bsum<<<1, 256, 0, stream>>>(bsum, nb);
    scan_apply<<<nb, 256, 0, stream>>>(deg, bsum, rowptr, bcur, N, E);
    bin_edges2<<<(E + BIN_CHUNK - 1) / BIN_CHUNK, 256, 0, stream>>>(ei, bcur, ebuf, E);
    distribute<<<NBKT, 256, 0, stream>>>(ebuf, rowptr, colarr, N);

    int gLin = (N + 63) / 64;   // 1563

    // Layer 0: agg7 -> lin7 (bf16 t0 -> XB0) -> mlp0, x1 -> XB1 (bf16)
    agg7<<<(N + 31) / 32, 256, 0, stream>>>(x, rowptr, colarr, h0, N);
    lin7<<<(N + 7) / 8, 256, 0, stream>>>(h0, W0a, b0a, XB0, N);
    mlp_fused<false, false, false, true><<<gLin, 256, 0, stream>>>(
        XB0, rowptr, colarr,
        nullptr, nullptr, nullptr,
        wfH + 0 * 16384, wfL + 0 * 16384, b0b,
        wfH + 5 * 16384, wfL + 5 * 16384, nullptr,
        batch, XB1, pooled, N);

    // Layer 1: bf16 gather XB1 -> MLP -> x2 -> XB2 (bf16)
    mlp_fused<true, true, false, true><<<gLin, 256, 0, stream>>>(
        XB1, rowptr, colarr,
        wfH + 1 * 16384, wfL + 1 * 16384, b1a,
        wfH + 2 * 16384, wfL + 2 * 16384, b1b,
        wfH + 6 * 16384, wfL + 6 * 16384, nullptr,
        batch, XB2, pooled, N);

    // Layer 2: bf16 gather XB2 -> MLP -> jk2 (x3 never materialized)
    mlp_fused<true, true, true, false><<<gLin, 256, 0, stream>>>(
        XB2, rowptr, colarr,
        wfH + 3 * 16384, wfL + 3 * 16384, b2a,
        wfH + 4 * 16384, wfL + 4 * 16384, b2b,
        wfH + 7 * 16384, wfL + 7 * 16384, bjk,
        batch, nullptr, pooled, N);

    classifier<<<B, 256, 0, stream>>>(pooled, Wc1, bc1, gamma, beta,
                                      rmean, rvar, Wc2, bc2, out);
}

// Round 4
// 481.269 us; speedup vs baseline: 1.4510x; 1.0558x over previous
//
#include <hip/hip_runtime.h>

#define NN 100000
#define EE 1600000
#define BB 256
#define IN_F 7
#define HH 128
#define NBKT 391        // ceil(NN/256) buckets for binned CSR fill
#define BIN_CHUNK 4096  // edges per bin_edges2 block

typedef unsigned int uint;
typedef unsigned short ushort;
typedef __attribute__((ext_vector_type(8))) short short8;
typedef __attribute__((ext_vector_type(4))) float f32x4;

// ---------------- bf16 helpers ----------------

__device__ __forceinline__ float bflo(uint u) { return __uint_as_float(u << 16); }
__device__ __forceinline__ float bfhi(uint u) { return __uint_as_float(u & 0xFFFF0000u); }
__device__ __forceinline__ ushort f2bf(float x) {   // RNE; inputs finite
    uint u = __float_as_uint(x);
    u = (u + 0x7FFFu + ((u >> 16) & 1u)) >> 16;
    return (ushort)u;
}

// ---------------- CSR build ----------------

__global__ void count_deg(const int* __restrict__ ei, int* __restrict__ deg, int e) {
    int i = blockIdx.x * 256 + threadIdx.x;
    if (i < e) atomicAdd(&deg[ei[e + i]], 1);   // dst = ei[E + i]
}

__global__ void scan_partial(const int* __restrict__ deg, int* __restrict__ bsum, int n) {
    __shared__ int sd[256];
    int b = blockIdx.x, t = threadIdx.x;
    int base = b * 1024 + t * 4;
    int s = 0;
    #pragma unroll
    for (int k = 0; k < 4; ++k) { int i = base + k; if (i < n) s += deg[i]; }
    sd[t] = s; __syncthreads();
    for (int off = 128; off > 0; off >>= 1) {
        if (t < off) sd[t] += sd[t + off];
        __syncthreads();
    }
    if (t == 0) bsum[b] = sd[0];
}

__global__ void scan_bsum(int* __restrict__ bsum, int nb) {
    __shared__ int sd[256];
    int t = threadIdx.x;
    int v = (t < nb) ? bsum[t] : 0;
    sd[t] = v; __syncthreads();
    for (int off = 1; off < 256; off <<= 1) {
        int add = (t >= off) ? sd[t - off] : 0;
        __syncthreads();
        sd[t] += add;
        __syncthreads();
    }
    if (t < nb) bsum[t] = sd[t] - v;   // exclusive
}

// also writes bcur[b] = rowptr[b*256] (init_bcur folded in)
__global__ void scan_apply(const int* __restrict__ deg, const int* __restrict__ bsum,
                           int* __restrict__ rowptr, int* __restrict__ bcur, int n, int e) {
    __shared__ int sd[256];
    int b = blockIdx.x, t = threadIdx.x;
    int base = b * 1024 + t * 4;
    int v[4]; int s = 0;
    #pragma unroll
    for (int k = 0; k < 4; ++k) { int i = base + k; v[k] = (i < n) ? deg[i] : 0; s += v[k]; }
    sd[t] = s; __syncthreads();
    int mine = s;
    for (int off = 1; off < 256; off <<= 1) {
        int add = (t >= off) ? sd[t - off] : 0;
        __syncthreads();
        sd[t] += add;
        __syncthreads();
    }
    int run = sd[t] - mine + bsum[b];
    #pragma unroll
    for (int k = 0; k < 4; ++k) {
        int i = base + k;
        if (i < n) {
            rowptr[i] = run;
            if ((i & 255) == 0) bcur[i >> 8] = run;
        }
        run += v[k];
    }
    if (b == 0 && t == 0) rowptr[n] = e;
}

// Pass A (two-level): per-block LDS histogram of the 391 buckets, one global
// atomicAdd per (block,bucket) to reserve a range, then LDS-cursor scatter.
// Packed entry: src (17b) | (dst&255) << 17.
__global__ __launch_bounds__(256) void bin_edges2(const int* __restrict__ ei,
        int* __restrict__ bcur, int* __restrict__ ebuf, int e) {
    __shared__ int hist[NBKT];
    __shared__ int base[NBKT];
    int t = threadIdx.x;
    int start = blockIdx.x * BIN_CHUNK;
    int end = start + BIN_CHUNK; if (end > e) end = e;
    for (int b = t; b < NBKT; b += 256) hist[b] = 0;
    __syncthreads();
    for (int i = start + t; i < end; i += 256)
        atomicAdd(&hist[ei[e + i] >> 8], 1);
    __syncthreads();
    for (int b = t; b < NBKT; b += 256) {
        int c = hist[b];
        base[b] = (c > 0) ? atomicAdd(&bcur[b], c) : 0;
        hist[b] = 0;
    }
    __syncthreads();
    for (int i = start + t; i < end; i += 256) {
        int d = ei[e + i], s = ei[i];
        int b = d >> 8;
        int pos = base[b] + atomicAdd(&hist[b], 1);
        ebuf[pos] = s | ((d & 255) << 17);
    }
}

// Pass B: one block per bucket; LDS cursors; colarr writes confined to the
// bucket's contiguous CSR region.
__global__ __launch_bounds__(256) void distribute(const int* __restrict__ ebuf,
        const int* __restrict__ rowptr, int* __restrict__ colarr, int n) {
    __shared__ int cur[256];
    int b = blockIdx.x, t = threadIdx.x;
    int n0 = b * 256;
    int n1 = n0 + 256; if (n1 > n) n1 = n;
    if (n0 + t < n1) cur[t] = rowptr[n0 + t];
    __syncthreads();
    int ebeg = rowptr[n0], eend = rowptr[n1];
    for (int i = ebeg + t; i < eend; i += 256) {
        int v = ebuf[i];
        int pos = atomicAdd(&cur[(v >> 17) & 255], 1);
        colarr[pos] = v & 0x1FFFF;
    }
}

// ---------------- weight pre-split (all 8 matrices, one launch) ----------------
// MFMA B-fragment layout: lane holds B[k=(lane>>4)*8+j][n=lane&15], j=0..7.
// Storage: [(kc*8+nt)*64 + lane]*8 + j. hi=bf16(W), lo=bf16(W-hi).

__global__ void wsplit_all(
        const float* __restrict__ w0, const float* __restrict__ w1,
        const float* __restrict__ w2, const float* __restrict__ w3,
        const float* __restrict__ w4, const float* __restrict__ w5,
        const float* __restrict__ w6, const float* __restrict__ w7,
        ushort* __restrict__ hiB, ushort* __restrict__ loB) {
    const float* ws[8] = {w0, w1, w2, w3, w4, w5, w6, w7};
    int gidx = blockIdx.x * 256 + threadIdx.x;   // 0..131071
    int mi = gidx >> 14;
    int idx = gidx & 16383;
    int j = idx & 7, l = (idx >> 3) & 63, blk = idx >> 9;
    int kc = blk >> 3, nt = blk & 7;
    int k = kc * 32 + (l >> 4) * 8 + j;
    int n = nt * 16 + (l & 15);
    float f = ws[mi][k * 128 + n];
    ushort h = f2bf(f);
    float hf = __uint_as_float((uint)h << 16);
    hiB[gidx] = h;
    loB[gidx] = f2bf(f - hf);
}

// ---------------- layer-0 aggregation (d=7) ----------------

__global__ __launch_bounds__(256) void agg7(const float* __restrict__ xin,
        const int* __restrict__ rowptr, const int* __restrict__ colarr,
        float* __restrict__ h0, int n) {
    int node = blockIdx.x * 32 + (threadIdx.x >> 3);
    int f = threadIdx.x & 7;
    if (node >= n) return;
    int fidx = (f < 7) ? f : 0;
    float acc = xin[node * 7 + fidx];
    int beg = rowptr[node], end = rowptr[node + 1];
    int j = beg;
    for (; j + 4 <= end; j += 4) {
        int s0 = colarr[j], s1 = colarr[j+1], s2 = colarr[j+2], s3 = colarr[j+3];
        float v0 = xin[s0*7 + fidx], v1 = xin[s1*7 + fidx];
        float v2 = xin[s2*7 + fidx], v3 = xin[s3*7 + fidx];
        acc += (v0 + v1) + (v2 + v3);
    }
    for (; j < end; ++j) acc += xin[colarr[j]*7 + fidx];
    h0[node * 8 + f] = (f < 7) ? acc : 0.f;
}

// ---------------- small first linear (bf16 output, row-major XB0) ----------------

__global__ __launch_bounds__(256) void lin7(const float* __restrict__ h0,
        const float* __restrict__ W, const float* __restrict__ bias,
        ushort* __restrict__ out, int n) {
    __shared__ float wl[7][128];
    __shared__ float hl[8][8];
    int t = threadIdx.x;
    for (int l = t; l < 7 * 128; l += 256) wl[l >> 7][l & 127] = W[l];
    int row0 = blockIdx.x * 8;
    if (t < 64) {
        int r = t >> 3, k = t & 7;
        int gr = row0 + r;
        hl[r][k] = (gr < n) ? h0[gr * 8 + k] : 0.f;
    }
    __syncthreads();
    int c = t & 127, g = t >> 7;
    float bv = bias[c];
    #pragma unroll
    for (int i = 0; i < 4; ++i) {
        int r = g * 4 + i, gr = row0 + r;
        if (gr < n) {
            float acc = bv;
            #pragma unroll
            for (int k = 0; k < 7; ++k) acc += hl[r][k] * wl[k][c];
            out[gr * 128 + c] = f2bf(fmaxf(acc, 0.f));
        }
    }
}

// ------- fused [bf16 gather] + MFMA MLP + JK + pool (512 thr = 8 waves) -------
// R17: 512-thread blocks on the same 64-row / 32 KB tile. LDS-limited
// residency (~3 blocks/CU) now carries 24 waves/CU instead of 12 -> 2x the
// latency hiding for the random-row gather. Gather: 8 threads/row. GEMM:
// 8 waves x 1 nt column tile (acc[4 mi]); same total MFMA and B traffic.
// __launch_bounds__(512,6) caps VGPR at 85 (R3 used 84 with more state).

// element (r, cu) lives at bufHL[h][r][ ((cu>>3) ^ (r&7))*8 + (cu&7) ]
__device__ __forceinline__ int swch(int chunk, int r) { return chunk ^ (r & 7); }

__device__ __forceinline__ void gemm_mfma(
        const ushort* __restrict__ WH, const ushort* __restrict__ WL,
        const ushort (&bufHL)[2][64][128], int w, int lm, int lq, int l,
        f32x4 (&acc)[4])
{
    #pragma unroll
    for (int mi = 0; mi < 4; ++mi) acc[mi] = (f32x4){0.f, 0.f, 0.f, 0.f};
    const short8* BH = (const short8*)WH;
    const short8* BL = (const short8*)WL;
    #pragma unroll
    for (int kc = 0; kc < 4; ++kc) {
        short8 bh = BH[(kc * 8 + w) * 64 + l];
        short8 bl = BL[(kc * 8 + w) * 64 + l];
        #pragma unroll
        for (int mi = 0; mi < 4; ++mi) {
            int row = mi * 16 + lm;
            int ch = swch(kc * 4 + lq, row);
            short8 ah = *(const short8*)&bufHL[0][row][ch * 8];
            short8 al = *(const short8*)&bufHL[1][row][ch * 8];
            acc[mi] = __builtin_amdgcn_mfma_f32_16x16x32_bf16(ah, bh, acc[mi], 0, 0, 0);
            acc[mi] = __builtin_amdgcn_mfma_f32_16x16x32_bf16(al, bh, acc[mi], 0, 0, 0);
            acc[mi] = __builtin_amdgcn_mfma_f32_16x16x32_bf16(ah, bl, acc[mi], 0, 0, 0);
        }
    }
}

// relu + bias; write hi/lo back to LDS; optional row-major bf16 XB out
__device__ __forceinline__ void epi_store(f32x4 (&acc)[4], const float* __restrict__ bias,
        ushort (&bufHL)[2][64][128], int row0, int n, int w, int lm, int lq,
        ushort* __restrict__ xout)
{
    int col = w * 16 + lm;
    float bv = bias[col];
    #pragma unroll
    for (int mi = 0; mi < 4; ++mi) {
        #pragma unroll
        for (int rr = 0; rr < 4; ++rr) {
            int row = mi * 16 + lq * 4 + rr;
            int gr = row0 + row;
            float v = fmaxf(acc[mi][rr] + bv, 0.f);
            if (gr >= n) v = 0.f;
            ushort hi = f2bf(v);
            float hf = __uint_as_float((uint)hi << 16);
            ushort lo = f2bf(v - hf);
            int off = (swch(col >> 3, row) << 3) | (col & 7);
            bufHL[0][row][off] = hi;
            bufHL[1][row][off] = lo;
            if (xout != nullptr && gr < n)
                xout[(size_t)gr * 128 + col] = hi;
        }
    }
}

template<bool GATHER, bool DO_A, bool LASTB, bool WRITE_X>
__global__ __launch_bounds__(512, 6) void mlp_fused(
        const ushort* __restrict__ in_bf,
        const int* __restrict__ rowptr, const int* __restrict__ colarr,
        const ushort* __restrict__ WaH, const ushort* __restrict__ WaL,
        const float* __restrict__ ba,
        const ushort* __restrict__ WbH, const ushort* __restrict__ WbL,
        const float* __restrict__ bb,
        const ushort* __restrict__ WjH, const ushort* __restrict__ WjL,
        const float* __restrict__ bjk,
        const int* __restrict__ batch,
        ushort* __restrict__ xout_bf, float* __restrict__ pooled, int n)
{
    __shared__ __align__(16) ushort bufHL[2][64][128];   // 32 KB (hi | lo)
    int t = threadIdx.x;
    int row0 = blockIdx.x * 64;

    if (GATHER) {
        // LDS-staged indices; 8 threads/row, 2 uint4 chunks each; x2 unroll.
        int* idx_lds = (int*)&bufHL[0][0][0];      // capacity 8192 ints (32 KB)
        int rlast = row0 + 64; if (rlast > n) rlast = n;
        int eb = rowptr[row0];
        int cnt = rowptr[rlast] - eb;
        int staged = cnt < 8192 ? cnt : 8192;
        for (int i = t; i < staged; i += 512) idx_lds[i] = colarr[eb + i];
        __syncthreads();

        int r = t >> 3, q = t & 7;
        int gr = row0 + r;
        float f[2][8];
        #pragma unroll
        for (int i = 0; i < 2; ++i)
            #pragma unroll
            for (int j = 0; j < 8; ++j) f[i][j] = 0.f;
        if (gr < n) {
            const uint4* sp = (const uint4*)(in_bf + (size_t)gr * 128);
            #pragma unroll
            for (int i = 0; i < 2; ++i) {
                uint4 v = sp[i * 8 + q];
                f[i][0] = bflo(v.x); f[i][1] = bfhi(v.x);
                f[i][2] = bflo(v.y); f[i][3] = bfhi(v.y);
                f[i][4] = bflo(v.z); f[i][5] = bfhi(v.z);
                f[i][6] = bflo(v.w); f[i][7] = bfhi(v.w);
            }
            int beg = rowptr[gr] - eb, end = rowptr[gr + 1] - eb;
            int j = beg;
            for (; j + 2 <= end; j += 2) {
                int s0 = (j     < staged) ? idx_lds[j]     : colarr[eb + j];
                int s1 = (j + 1 < staged) ? idx_lds[j + 1] : colarr[eb + j + 1];
                const uint4* n0 = (const uint4*)(in_bf + (size_t)s0 * 128);
                const uint4* n1 = (const uint4*)(in_bf + (size_t)s1 * 128);
                uint4 v0[2], v1[2];
                #pragma unroll
                for (int i = 0; i < 2; ++i) { v0[i] = n0[i * 8 + q]; v1[i] = n1[i * 8 + q]; }
                #pragma unroll
                for (int i = 0; i < 2; ++i) {
                    f[i][0] += bflo(v0[i].x) + bflo(v1[i].x);
                    f[i][1] += bfhi(v0[i].x) + bfhi(v1[i].x);
                    f[i][2] += bflo(v0[i].y) + bflo(v1[i].y);
                    f[i][3] += bfhi(v0[i].y) + bfhi(v1[i].y);
                    f[i][4] += bflo(v0[i].z) + bflo(v1[i].z);
                    f[i][5] += bfhi(v0[i].z) + bfhi(v1[i].z);
                    f[i][6] += bflo(v0[i].w) + bflo(v1[i].w);
                    f[i][7] += bfhi(v0[i].w) + bfhi(v1[i].w);
                }
            }
            for (; j < end; ++j) {
                int s0 = (j < staged) ? idx_lds[j] : colarr[eb + j];
                const uint4* np = (const uint4*)(in_bf + (size_t)s0 * 128);
                #pragma unroll
                for (int i = 0; i < 2; ++i) {
                    uint4 v = np[i * 8 + q];
                    f[i][0] += bflo(v.x); f[i][1] += bfhi(v.x);
                    f[i][2] += bflo(v.y); f[i][3] += bfhi(v.y);
                    f[i][4] += bflo(v.z); f[i][5] += bfhi(v.z);
                    f[i][6] += bflo(v.w); f[i][7] += bfhi(v.w);
                }
            }
        }
        __syncthreads();   // all idx_lds reads done before bufHL is overwritten
        #pragma unroll
        for (int i = 0; i < 2; ++i) {
            short8 hi8, lo8;
            #pragma unroll
            for (int j = 0; j < 8; ++j) {
                ushort h = f2bf(f[i][j]);
                hi8[j] = (short)h;
                float hf = __uint_as_float((uint)h << 16);
                lo8[j] = (short)f2bf(f[i][j] - hf);
            }
            int ch = swch(i * 8 + q, r);
            *(short8*)&bufHL[0][r][ch * 8] = hi8;
            *(short8*)&bufHL[1][r][ch * 8] = lo8;
        }
    } else {
        // bf16 staging of t0: hi = input (already bf16), lo = 0
        #pragma unroll
        for (int it = 0; it < 2; ++it) {
            int lidx = t + 512 * it;
            int r = lidx >> 4, c = lidx & 15;
            int gr = row0 + r;
            uint4 v = make_uint4(0u, 0u, 0u, 0u);
            if (gr < n) v = *(const uint4*)&in_bf[(size_t)gr * 128 + c * 8];
            int ch = swch(c, r);
            *(uint4*)&bufHL[0][r][ch * 8] = v;
            *(uint4*)&bufHL[1][r][ch * 8] = make_uint4(0u, 0u, 0u, 0u);
        }
    }
    __syncthreads();

    int w = t >> 6, l = t & 63;
    int lm = l & 15, lq = l >> 4;
    f32x4 acc[4];

    if (DO_A) {
        gemm_mfma(WaH, WaL, bufHL, w, lm, lq, l, acc);
        __syncthreads();
        epi_store(acc, ba, bufHL, row0, n, w, lm, lq, nullptr);
        __syncthreads();
    }

    gemm_mfma(WbH, WbL, bufHL, w, lm, lq, l, acc);
    __syncthreads();
    epi_store(acc, bb, bufHL, row0, n, w, lm, lq, WRITE_X ? xout_bf : nullptr);
    __syncthreads();

    gemm_mfma(WjH, WjL, bufHL, w, lm, lq, l, acc);
    __syncthreads();

    // JK epilogue: +bjk (last layer), mask invalid rows, stage hi/lo into LDS
    {
        int col = w * 16 + lm;
        float bv = LASTB ? bjk[col] : 0.f;
        #pragma unroll
        for (int mi = 0; mi < 4; ++mi) {
            #pragma unroll
            for (int rr = 0; rr < 4; ++rr) {
                int row = mi * 16 + lq * 4 + rr;
                int gr = row0 + row;
                float v = acc[mi][rr] + bv;
                if (gr >= n) v = 0.f;
                ushort hi = f2bf(v);
                float hf = __uint_as_float((uint)hi << 16);
                ushort lo = f2bf(v - hf);
                int off = (swch(col >> 3, row) << 3) | (col & 7);
                bufHL[0][row][off] = hi;
                bufHL[1][row][off] = lo;
            }
        }
    }
    __syncthreads();

    // pooling (values decoded as hi+lo; ~2^-17 rel error, negligible)
    int row_last = row0 + 63; if (row_last > n - 1) row_last = n - 1;
    int g_first = batch[row0];
    int g_last  = batch[row_last];
    int c = t & 127, qh = t >> 7;   // 4 quarters x 16 rows
    if (g_first == g_last) {
        float sacc = 0.f;
        #pragma unroll 4
        for (int r = qh * 16; r < qh * 16 + 16; ++r) {
            int off = (swch(c >> 3, r) << 3) | (c & 7);
            sacc += __uint_as_float((uint)bufHL[0][r][off] << 16)
                  + __uint_as_float((uint)bufHL[1][r][off] << 16);
        }
        __syncthreads();
        float* scr = (float*)&bufHL[0][0][0];   // 512 floats scratch
        scr[t] = sacc;
        __syncthreads();
        if (t < 128)
            atomicAdd(&pooled[g_first * 128 + t],
                      (scr[t] + scr[t + 128]) + (scr[t + 256] + scr[t + 384]));
    } else {
        float sacc = 0.f; int gprev = -1;
        for (int r = qh * 16; r < qh * 16 + 16; ++r) {
            int gr = row0 + r;
            if (gr >= n) break;
            int g = batch[gr];
            if (g != gprev) {
                if (gprev >= 0) atomicAdd(&pooled[gprev * 128 + c], sacc);
                sacc = 0.f; gprev = g;
            }
            int off = (swch(c >> 3, r) << 3) | (c & 7);
            sacc += __uint_as_float((uint)bufHL[0][r][off] << 16)
                  + __uint_as_float((uint)bufHL[1][r][off] << 16);
        }
        if (gprev >= 0) atomicAdd(&pooled[gprev * 128 + c], sacc);
    }
}

// ---------------- classifier ----------------

__global__ __launch_bounds__(256) void classifier(const float* __restrict__ pooled,
        const float* __restrict__ Wc1, const float* __restrict__ bc1,
        const float* __restrict__ gamma, const float* __restrict__ beta,
        const float* __restrict__ rmean, const float* __restrict__ rvar,
        const float* __restrict__ Wc2, const float* __restrict__ bc2,
        float* __restrict__ out) {
    int g = blockIdx.x, t = threadIdx.x;
    __shared__ float p[128];
    __shared__ float r0[256], r1[256];
    if (t < 128) p[t] = pooled[g * 128 + t];
    __syncthreads();
    float acc = bc1[t];
    #pragma unroll 8
    for (int k = 0; k < 128; ++k) acc += p[k] * Wc1[k * 256 + t];
    float z = (acc - rmean[t]) * rsqrtf(rvar[t] + 1e-5f) * gamma[t] + beta[t];
    z = fmaxf(z, 0.f);
    r0[t] = z * Wc2[t * 2 + 0];
    r1[t] = z * Wc2[t * 2 + 1];
    __syncthreads();
    for (int s = 128; s > 0; s >>= 1) {
        if (t < s) { r0[t] += r0[t + s]; r1[t] += r1[t + s]; }
        __syncthreads();
    }
    if (t == 0) {
        out[g * 2 + 0] = r0[0] + bc2[0];
        out[g * 2 + 1] = r1[0] + bc2[1];
    }
}

// ---------------- launch ----------------

static inline size_t al256(size_t x) { return (x + 255) & ~size_t(255); }

extern "C" void kernel_launch(void* const* d_in, const int* in_sizes, int n_in,
                              void* d_out, int out_size, void* d_ws, size_t ws_size,
                              hipStream_t stream) {
    const float* x    = (const float*)d_in[0];
    const int*   ei   = (const int*)  d_in[1];
    const int*   batch= (const int*)  d_in[3];
    const float* W0a = (const float*)d_in[4];  const float* b0a = (const float*)d_in[5];
    const float* W0b = (const float*)d_in[6];  const float* b0b = (const float*)d_in[7];
    const float* W1a = (const float*)d_in[8];  const float* b1a = (const float*)d_in[9];
    const float* W1b = (const float*)d_in[10]; const float* b1b = (const float*)d_in[11];
    const float* W2a = (const float*)d_in[12]; const float* b2a = (const float*)d_in[13];
    const float* W2b = (const float*)d_in[14]; const float* b2b = (const float*)d_in[15];
    const float* Wjk = (const float*)d_in[16]; const float* bjk = (const float*)d_in[17];
    const float* Wc1 = (const float*)d_in[18]; const float* bc1 = (const float*)d_in[19];
    const float* gamma=(const float*)d_in[20]; const float* beta= (const float*)d_in[21];
    const float* rmean=(const float*)d_in[22]; const float* rvar= (const float*)d_in[23];
    const float* Wc2 = (const float*)d_in[24]; const float* bc2 = (const float*)d_in[25];
    float* out = (float*)d_out;

    const int N = NN, E = EE, B = BB;

    char* w = (char*)d_ws;
    size_t off = 0;
    int* deg    = (int*)(w + off); off = al256(off + (size_t)N * 4);
    int* rowptr = (int*)(w + off); off = al256(off + (size_t)(N + 1) * 4);
    int* bcur   = (int*)(w + off); off = al256(off + (size_t)NBKT * 4);
    int* colarr = (int*)(w + off); off = al256(off + (size_t)E * 4);
    int* ebuf   = (int*)(w + off); off = al256(off + (size_t)E * 4);
    int* bsum   = (int*)(w + off); off = al256(off + 1024 * 4);
    float* h0   = (float*)(w + off); off = al256(off + (size_t)N * 8 * 4);
    ushort* XB0 = (ushort*)(w + off); off = al256(off + (size_t)N * 128 * 2);
    ushort* XB1 = (ushort*)(w + off); off = al256(off + (size_t)N * 128 * 2);
    ushort* XB2 = (ushort*)(w + off); off = al256(off + (size_t)N * 128 * 2);
    float* pooled = (float*)(w + off); off = al256(off + (size_t)B * 128 * 4);
    ushort* wfH = (ushort*)(w + off); off = al256(off + (size_t)8 * 16384 * 2);
    ushort* wfL = (ushort*)(w + off); off = al256(off + (size_t)8 * 16384 * 2);

    hipMemsetAsync(deg, 0, (size_t)N * 4, stream);
    hipMemsetAsync(pooled, 0, (size_t)B * 128 * 4, stream);

    // pre-split weights (order: W0b, W1a, W1b, W2a, W2b, Wjk0, Wjk1, Wjk2)
    wsplit_all<<<512, 256, 0, stream>>>(W0b, W1a, W1b, W2a, W2b,
                                        Wjk, Wjk + 128 * 128, Wjk + 256 * 128,
                                        wfH, wfL);

    int nb = (N + 1023) / 1024;   // 98

    count_deg<<<(E + 255) / 256, 256, 0, stream>>>(ei, deg, E);
    scan_partial<<<nb, 256, 0, stream>>>(deg, bsum, N);
    scan_bsum<<<1, 256, 0, stream>>>(bsum, nb);
    scan_apply<<<nb, 256, 0, stream>>>(deg, bsum, rowptr, bcur, N, E);
    bin_edges2<<<(E + BIN_CHUNK - 1) / BIN_CHUNK, 256, 0, stream>>>(ei, bcur, ebuf, E);
    distribute<<<NBKT, 256, 0, stream>>>(ebuf, rowptr, colarr, N);

    int gLin = (N + 63) / 64;   // 1563

    // Layer 0: agg7 -> lin7 (bf16 t0 -> XB0) -> mlp0, x1 -> XB1 (bf16)
    agg7<<<(N + 31) / 32, 256, 0, stream>>>(x, rowptr, colarr, h0, N);
    lin7<<<(N + 7) / 8, 256, 0, stream>>>(h0, W0a, b0a, XB0, N);
    mlp_fused<false, false, false, true><<<gLin, 512, 0, stream>>>(
        XB0, rowptr, colarr,
        nullptr, nullptr, nullptr,
        wfH + 0 * 16384, wfL + 0 * 16384, b0b,
        wfH + 5 * 16384, wfL + 5 * 16384, nullptr,
        batch, XB1, pooled, N);

    // Layer 1: bf16 gather XB1 -> MLP -> x2 -> XB2 (bf16)
    mlp_fused<true, true, false, true><<<gLin, 512, 0, stream>>>(
        XB1, rowptr, colarr,
        wfH + 1 * 16384, wfL + 1 * 16384, b1a,
        wfH + 2 * 16384, wfL + 2 * 16384, b1b,
        wfH + 6 * 16384, wfL + 6 * 16384, nullptr,
        batch, XB2, pooled, N);

    // Layer 2: bf16 gather XB2 -> MLP -> jk2 (x3 never materialized)
    mlp_fused<true, true, true, false><<<gLin, 512, 0, stream>>>(
        XB2, rowptr, colarr,
        wfH + 3 * 16384, wfL + 3 * 16384, b2a,
        wfH + 4 * 16384, wfL + 4 * 16384, b2b,
        wfH + 7 * 16384, wfL + 7 * 16384, bjk,
        batch, nullptr, pooled, N);

    classifier<<<B, 256, 0, stream>>>(pooled, Wc1, bc1, gamma, beta,
                                      rmean, rvar, Wc2, bc2, out);
}

// Round 5
// 463.405 us; speedup vs baseline: 1.5069x; 1.0385x over previous
//
#include <hip/hip_runtime.h>

#define NN 100000
#define EE 1600000
#define BB 256
#define IN_F 7
#define HH 128
#define NBKT 391        // ceil(NN/256) buckets for binned CSR fill
#define BIN_CHUNK 4096  // edges per bin_edges2 block

typedef unsigned int uint;
typedef unsigned short ushort;
typedef __attribute__((ext_vector_type(8))) short short8;
typedef __attribute__((ext_vector_type(4))) float f32x4;

// ---------------- bf16 helpers ----------------

__device__ __forceinline__ float bflo(uint u) { return __uint_as_float(u << 16); }
__device__ __forceinline__ float bfhi(uint u) { return __uint_as_float(u & 0xFFFF0000u); }
__device__ __forceinline__ ushort f2bf(float x) {   // RNE; inputs finite
    uint u = __float_as_uint(x);
    u = (u + 0x7FFFu + ((u >> 16) & 1u)) >> 16;
    return (ushort)u;
}

// ---------------- CSR build ----------------

__global__ void count_deg(const int* __restrict__ ei, int* __restrict__ deg, int e) {
    int i = blockIdx.x * 256 + threadIdx.x;
    if (i < e) atomicAdd(&deg[ei[e + i]], 1);   // dst = ei[E + i]
}

__global__ void scan_partial(const int* __restrict__ deg, int* __restrict__ bsum, int n) {
    __shared__ int sd[256];
    int b = blockIdx.x, t = threadIdx.x;
    int base = b * 1024 + t * 4;
    int s = 0;
    #pragma unroll
    for (int k = 0; k < 4; ++k) { int i = base + k; if (i < n) s += deg[i]; }
    sd[t] = s; __syncthreads();
    for (int off = 128; off > 0; off >>= 1) {
        if (t < off) sd[t] += sd[t + off];
        __syncthreads();
    }
    if (t == 0) bsum[b] = sd[0];
}

__global__ void scan_bsum(int* __restrict__ bsum, int nb) {
    __shared__ int sd[256];
    int t = threadIdx.x;
    int v = (t < nb) ? bsum[t] : 0;
    sd[t] = v; __syncthreads();
    for (int off = 1; off < 256; off <<= 1) {
        int add = (t >= off) ? sd[t - off] : 0;
        __syncthreads();
        sd[t] += add;
        __syncthreads();
    }
    if (t < nb) bsum[t] = sd[t] - v;   // exclusive
}

// also writes bcur[b] = rowptr[b*256] (init_bcur folded in)
__global__ void scan_apply(const int* __restrict__ deg, const int* __restrict__ bsum,
                           int* __restrict__ rowptr, int* __restrict__ bcur, int n, int e) {
    __shared__ int sd[256];
    int b = blockIdx.x, t = threadIdx.x;
    int base = b * 1024 + t * 4;
    int v[4]; int s = 0;
    #pragma unroll
    for (int k = 0; k < 4; ++k) { int i = base + k; v[k] = (i < n) ? deg[i] : 0; s += v[k]; }
    sd[t] = s; __syncthreads();
    int mine = s;
    for (int off = 1; off < 256; off <<= 1) {
        int add = (t >= off) ? sd[t - off] : 0;
        __syncthreads();
        sd[t] += add;
        __syncthreads();
    }
    int run = sd[t] - mine + bsum[b];
    #pragma unroll
    for (int k = 0; k < 4; ++k) {
        int i = base + k;
        if (i < n) {
            rowptr[i] = run;
            if ((i & 255) == 0) bcur[i >> 8] = run;
        }
        run += v[k];
    }
    if (b == 0 && t == 0) rowptr[n] = e;
}

// Pass A (two-level): per-block LDS histogram of the 391 buckets, one global
// atomicAdd per (block,bucket) to reserve a range, then LDS-cursor scatter.
// Packed entry: src (17b) | (dst&255) << 17.
__global__ __launch_bounds__(256) void bin_edges2(const int* __restrict__ ei,
        int* __restrict__ bcur, int* __restrict__ ebuf, int e) {
    __shared__ int hist[NBKT];
    __shared__ int base[NBKT];
    int t = threadIdx.x;
    int start = blockIdx.x * BIN_CHUNK;
    int end = start + BIN_CHUNK; if (end > e) end = e;
    for (int b = t; b < NBKT; b += 256) hist[b] = 0;
    __syncthreads();
    for (int i = start + t; i < end; i += 256)
        atomicAdd(&hist[ei[e + i] >> 8], 1);
    __syncthreads();
    for (int b = t; b < NBKT; b += 256) {
        int c = hist[b];
        base[b] = (c > 0) ? atomicAdd(&bcur[b], c) : 0;
        hist[b] = 0;
    }
    __syncthreads();
    for (int i = start + t; i < end; i += 256) {
        int d = ei[e + i], s = ei[i];
        int b = d >> 8;
        int pos = base[b] + atomicAdd(&hist[b], 1);
        ebuf[pos] = s | ((d & 255) << 17);
    }
}

// Pass B: one block per bucket; LDS cursors; colarr writes confined to the
// bucket's contiguous CSR region.
__global__ __launch_bounds__(256) void distribute(const int* __restrict__ ebuf,
        const int* __restrict__ rowptr, int* __restrict__ colarr, int n) {
    __shared__ int cur[256];
    int b = blockIdx.x, t = threadIdx.x;
    int n0 = b * 256;
    int n1 = n0 + 256; if (n1 > n) n1 = n;
    if (n0 + t < n1) cur[t] = rowptr[n0 + t];
    __syncthreads();
    int ebeg = rowptr[n0], eend = rowptr[n1];
    for (int i = ebeg + t; i < eend; i += 256) {
        int v = ebuf[i];
        int pos = atomicAdd(&cur[(v >> 17) & 255], 1);
        colarr[pos] = v & 0x1FFFF;
    }
}

// ---------------- weight pre-split (all 8 matrices, one launch) ----------------
// MFMA B-fragment layout: lane holds B[k=(lane>>4)*8+j][n=lane&15], j=0..7.
// Storage: [(kc*8+nt)*64 + lane]*8 + j. hi=bf16(W), lo=bf16(W-hi).

__global__ void wsplit_all(
        const float* __restrict__ w0, const float* __restrict__ w1,
        const float* __restrict__ w2, const float* __restrict__ w3,
        const float* __restrict__ w4, const float* __restrict__ w5,
        const float* __restrict__ w6, const float* __restrict__ w7,
        ushort* __restrict__ hiB, ushort* __restrict__ loB) {
    const float* ws[8] = {w0, w1, w2, w3, w4, w5, w6, w7};
    int gidx = blockIdx.x * 256 + threadIdx.x;   // 0..131071
    int mi = gidx >> 14;
    int idx = gidx & 16383;
    int j = idx & 7, l = (idx >> 3) & 63, blk = idx >> 9;
    int kc = blk >> 3, nt = blk & 7;
    int k = kc * 32 + (l >> 4) * 8 + j;
    int n = nt * 16 + (l & 15);
    float f = ws[mi][k * 128 + n];
    ushort h = f2bf(f);
    float hf = __uint_as_float((uint)h << 16);
    hiB[gidx] = h;
    loB[gidx] = f2bf(f - hf);
}

// ---------------- layer-0 aggregation (d=7) ----------------

__global__ __launch_bounds__(256) void agg7(const float* __restrict__ xin,
        const int* __restrict__ rowptr, const int* __restrict__ colarr,
        float* __restrict__ h0, int n) {
    int node = blockIdx.x * 32 + (threadIdx.x >> 3);
    int f = threadIdx.x & 7;
    if (node >= n) return;
    int fidx = (f < 7) ? f : 0;
    float acc = xin[node * 7 + fidx];
    int beg = rowptr[node], end = rowptr[node + 1];
    int j = beg;
    for (; j + 4 <= end; j += 4) {
        int s0 = colarr[j], s1 = colarr[j+1], s2 = colarr[j+2], s3 = colarr[j+3];
        float v0 = xin[s0*7 + fidx], v1 = xin[s1*7 + fidx];
        float v2 = xin[s2*7 + fidx], v3 = xin[s3*7 + fidx];
        acc += (v0 + v1) + (v2 + v3);
    }
    for (; j < end; ++j) acc += xin[colarr[j]*7 + fidx];
    h0[node * 8 + f] = (f < 7) ? acc : 0.f;
}

// ---------------- small first linear (bf16 output, row-major XB0) ----------------

__global__ __launch_bounds__(256) void lin7(const float* __restrict__ h0,
        const float* __restrict__ W, const float* __restrict__ bias,
        ushort* __restrict__ out, int n) {
    __shared__ float wl[7][128];
    __shared__ float hl[8][8];
    int t = threadIdx.x;
    for (int l = t; l < 7 * 128; l += 256) wl[l >> 7][l & 127] = W[l];
    int row0 = blockIdx.x * 8;
    if (t < 64) {
        int r = t >> 3, k = t & 7;
        int gr = row0 + r;
        hl[r][k] = (gr < n) ? h0[gr * 8 + k] : 0.f;
    }
    __syncthreads();
    int c = t & 127, g = t >> 7;
    float bv = bias[c];
    #pragma unroll
    for (int i = 0; i < 4; ++i) {
        int r = g * 4 + i, gr = row0 + r;
        if (gr < n) {
            float acc = bv;
            #pragma unroll
            for (int k = 0; k < 7; ++k) acc += hl[r][k] * wl[k][c];
            out[gr * 128 + c] = f2bf(fmaxf(acc, 0.f));
        }
    }
}

// ------- fused [bf16 gather] + MFMA MLP + JK + pool (512 thr = 8 waves) -------
// R18: 32-row tile / 16 KB LDS. R4 showed workgroup-LDS packs only ~64 KB/CU:
// 32 KB blocks -> 2 blocks/CU = 16 waves (Occ 50%). 16 KB blocks -> 4 blocks/CU
// = 32 waves (wave-slot cap). Same totals of MFMA/LDS/gather work, 2x grid.
// Gather: 16 threads/row x 1 uint4 chunk. GEMM: 8 waves x 1 nt tile, acc[2 mi].

// element (r, cu) lives at bufHL[h][r][ ((cu>>3) ^ (r&7))*8 + (cu&7) ]
__device__ __forceinline__ int swch(int chunk, int r) { return chunk ^ (r & 7); }

__device__ __forceinline__ void gemm_mfma(
        const ushort* __restrict__ WH, const ushort* __restrict__ WL,
        const ushort (&bufHL)[2][32][128], int w, int lm, int lq, int l,
        f32x4 (&acc)[2])
{
    #pragma unroll
    for (int mi = 0; mi < 2; ++mi) acc[mi] = (f32x4){0.f, 0.f, 0.f, 0.f};
    const short8* BH = (const short8*)WH;
    const short8* BL = (const short8*)WL;
    #pragma unroll
    for (int kc = 0; kc < 4; ++kc) {
        short8 bh = BH[(kc * 8 + w) * 64 + l];
        short8 bl = BL[(kc * 8 + w) * 64 + l];
        #pragma unroll
        for (int mi = 0; mi < 2; ++mi) {
            int row = mi * 16 + lm;
            int ch = swch(kc * 4 + lq, row);
            short8 ah = *(const short8*)&bufHL[0][row][ch * 8];
            short8 al = *(const short8*)&bufHL[1][row][ch * 8];
            acc[mi] = __builtin_amdgcn_mfma_f32_16x16x32_bf16(ah, bh, acc[mi], 0, 0, 0);
            acc[mi] = __builtin_amdgcn_mfma_f32_16x16x32_bf16(al, bh, acc[mi], 0, 0, 0);
            acc[mi] = __builtin_amdgcn_mfma_f32_16x16x32_bf16(ah, bl, acc[mi], 0, 0, 0);
        }
    }
}

// relu + bias; write hi/lo back to LDS; optional row-major bf16 XB out
__device__ __forceinline__ void epi_store(f32x4 (&acc)[2], const float* __restrict__ bias,
        ushort (&bufHL)[2][32][128], int row0, int n, int w, int lm, int lq,
        ushort* __restrict__ xout)
{
    int col = w * 16 + lm;
    float bv = bias[col];
    #pragma unroll
    for (int mi = 0; mi < 2; ++mi) {
        #pragma unroll
        for (int rr = 0; rr < 4; ++rr) {
            int row = mi * 16 + lq * 4 + rr;
            int gr = row0 + row;
            float v = fmaxf(acc[mi][rr] + bv, 0.f);
            if (gr >= n) v = 0.f;
            ushort hi = f2bf(v);
            float hf = __uint_as_float((uint)hi << 16);
            ushort lo = f2bf(v - hf);
            int off = (swch(col >> 3, row) << 3) | (col & 7);
            bufHL[0][row][off] = hi;
            bufHL[1][row][off] = lo;
            if (xout != nullptr && gr < n)
                xout[(size_t)gr * 128 + col] = hi;
        }
    }
}

template<bool GATHER, bool DO_A, bool LASTB, bool WRITE_X>
__global__ __launch_bounds__(512, 8) void mlp_fused(
        const ushort* __restrict__ in_bf,
        const int* __restrict__ rowptr, const int* __restrict__ colarr,
        const ushort* __restrict__ WaH, const ushort* __restrict__ WaL,
        const float* __restrict__ ba,
        const ushort* __restrict__ WbH, const ushort* __restrict__ WbL,
        const float* __restrict__ bb,
        const ushort* __restrict__ WjH, const ushort* __restrict__ WjL,
        const float* __restrict__ bjk,
        const int* __restrict__ batch,
        ushort* __restrict__ xout_bf, float* __restrict__ pooled, int n)
{
    __shared__ __align__(16) ushort bufHL[2][32][128];   // 16 KB (hi | lo)
    int t = threadIdx.x;
    int row0 = blockIdx.x * 32;

    if (GATHER) {
        // LDS-staged indices; 16 threads/row, 1 uint4 chunk each; x2 unroll.
        int* idx_lds = (int*)&bufHL[0][0][0];      // capacity 4096 ints (16 KB)
        int rlast = row0 + 32; if (rlast > n) rlast = n;
        int eb = rowptr[row0];
        int cnt = rowptr[rlast] - eb;
        int staged = cnt < 4096 ? cnt : 4096;
        for (int i = t; i < staged; i += 512) idx_lds[i] = colarr[eb + i];
        __syncthreads();

        int r = t >> 4, q = t & 15;
        int gr = row0 + r;
        float f[8];
        #pragma unroll
        for (int j = 0; j < 8; ++j) f[j] = 0.f;
        if (gr < n) {
            const uint4* sp = (const uint4*)(in_bf + (size_t)gr * 128);
            uint4 v = sp[q];
            f[0] = bflo(v.x); f[1] = bfhi(v.x);
            f[2] = bflo(v.y); f[3] = bfhi(v.y);
            f[4] = bflo(v.z); f[5] = bfhi(v.z);
            f[6] = bflo(v.w); f[7] = bfhi(v.w);
            int beg = rowptr[gr] - eb, end = rowptr[gr + 1] - eb;
            int j = beg;
            for (; j + 2 <= end; j += 2) {
                int s0 = (j     < staged) ? idx_lds[j]     : colarr[eb + j];
                int s1 = (j + 1 < staged) ? idx_lds[j + 1] : colarr[eb + j + 1];
                uint4 v0 = ((const uint4*)(in_bf + (size_t)s0 * 128))[q];
                uint4 v1 = ((const uint4*)(in_bf + (size_t)s1 * 128))[q];
                f[0] += bflo(v0.x) + bflo(v1.x);
                f[1] += bfhi(v0.x) + bfhi(v1.x);
                f[2] += bflo(v0.y) + bflo(v1.y);
                f[3] += bfhi(v0.y) + bfhi(v1.y);
                f[4] += bflo(v0.z) + bflo(v1.z);
                f[5] += bfhi(v0.z) + bfhi(v1.z);
                f[6] += bflo(v0.w) + bflo(v1.w);
                f[7] += bfhi(v0.w) + bfhi(v1.w);
            }
            for (; j < end; ++j) {
                int s0 = (j < staged) ? idx_lds[j] : colarr[eb + j];
                uint4 v2 = ((const uint4*)(in_bf + (size_t)s0 * 128))[q];
                f[0] += bflo(v2.x); f[1] += bfhi(v2.x);
                f[2] += bflo(v2.y); f[3] += bfhi(v2.y);
                f[4] += bflo(v2.z); f[5] += bfhi(v2.z);
                f[6] += bflo(v2.w); f[7] += bfhi(v2.w);
            }
        }
        __syncthreads();   // all idx_lds reads done before bufHL is overwritten
        {
            short8 hi8, lo8;
            #pragma unroll
            for (int j = 0; j < 8; ++j) {
                ushort h = f2bf(f[j]);
                hi8[j] = (short)h;
                float hf = __uint_as_float((uint)h << 16);
                lo8[j] = (short)f2bf(f[j] - hf);
            }
            int ch = swch(q, r);
            *(short8*)&bufHL[0][r][ch * 8] = hi8;
            *(short8*)&bufHL[1][r][ch * 8] = lo8;
        }
    } else {
        // bf16 staging of t0: hi = input (already bf16), lo = 0; one chunk each
        int r = t >> 4, c = t & 15;
        int gr = row0 + r;
        uint4 v = make_uint4(0u, 0u, 0u, 0u);
        if (gr < n) v = *(const uint4*)&in_bf[(size_t)gr * 128 + c * 8];
        int ch = swch(c, r);
        *(uint4*)&bufHL[0][r][ch * 8] = v;
        *(uint4*)&bufHL[1][r][ch * 8] = make_uint4(0u, 0u, 0u, 0u);
    }
    __syncthreads();

    int w = t >> 6, l = t & 63;
    int lm = l & 15, lq = l >> 4;
    f32x4 acc[2];

    if (DO_A) {
        gemm_mfma(WaH, WaL, bufHL, w, lm, lq, l, acc);
        __syncthreads();
        epi_store(acc, ba, bufHL, row0, n, w, lm, lq, nullptr);
        __syncthreads();
    }

    gemm_mfma(WbH, WbL, bufHL, w, lm, lq, l, acc);
    __syncthreads();
    epi_store(acc, bb, bufHL, row0, n, w, lm, lq, WRITE_X ? xout_bf : nullptr);
    __syncthreads();

    gemm_mfma(WjH, WjL, bufHL, w, lm, lq, l, acc);
    __syncthreads();

    // JK epilogue: +bjk (last layer), mask invalid rows, stage hi/lo into LDS
    {
        int col = w * 16 + lm;
        float bv = LASTB ? bjk[col] : 0.f;
        #pragma unroll
        for (int mi = 0; mi < 2; ++mi) {
            #pragma unroll
            for (int rr = 0; rr < 4; ++rr) {
                int row = mi * 16 + lq * 4 + rr;
                int gr = row0 + row;
                float v = acc[mi][rr] + bv;
                if (gr >= n) v = 0.f;
                ushort hi = f2bf(v);
                float hf = __uint_as_float((uint)hi << 16);
                ushort lo = f2bf(v - hf);
                int off = (swch(col >> 3, row) << 3) | (col & 7);
                bufHL[0][row][off] = hi;
                bufHL[1][row][off] = lo;
            }
        }
    }
    __syncthreads();

    // pooling (values decoded as hi+lo; ~2^-17 rel error, negligible)
    int row_last = row0 + 31; if (row_last > n - 1) row_last = n - 1;
    int g_first = batch[row0];
    int g_last  = batch[row_last];
    int c = t & 127, qh = t >> 7;   // 4 quarters x 8 rows
    if (g_first == g_last) {
        float sacc = 0.f;
        #pragma unroll 4
        for (int r = qh * 8; r < qh * 8 + 8; ++r) {
            int off = (swch(c >> 3, r) << 3) | (c & 7);
            sacc += __uint_as_float((uint)bufHL[0][r][off] << 16)
                  + __uint_as_float((uint)bufHL[1][r][off] << 16);
        }
        __syncthreads();
        float* scr = (float*)&bufHL[0][0][0];   // 512 floats scratch
        scr[t] = sacc;
        __syncthreads();
        if (t < 128)
            atomicAdd(&pooled[g_first * 128 + t],
                      (scr[t] + scr[t + 128]) + (scr[t + 256] + scr[t + 384]));
    } else {
        float sacc = 0.f; int gprev = -1;
        for (int r = qh * 8; r < qh * 8 + 8; ++r) {
            int gr = row0 + r;
            if (gr >= n) break;
            int g = batch[gr];
            if (g != gprev) {
                if (gprev >= 0) atomicAdd(&pooled[gprev * 128 + c], sacc);
                sacc = 0.f; gprev = g;
            }
            int off = (swch(c >> 3, r) << 3) | (c & 7);
            sacc += __uint_as_float((uint)bufHL[0][r][off] << 16)
                  + __uint_as_float((uint)bufHL[1][r][off] << 16);
        }
        if (gprev >= 0) atomicAdd(&pooled[gprev * 128 + c], sacc);
    }
}

// ---------------- classifier ----------------

__global__ __launch_bounds__(256) void classifier(const float* __restrict__ pooled,
        const float* __restrict__ Wc1, const float* __restrict__ bc1,
        const float* __restrict__ gamma, const float* __restrict__ beta,
        const float* __restrict__ rmean, const float* __restrict__ rvar,
        const float* __restrict__ Wc2, const float* __restrict__ bc2,
        float* __restrict__ out) {
    int g = blockIdx.x, t = threadIdx.x;
    __shared__ float p[128];
    __shared__ float r0[256], r1[256];
    if (t < 128) p[t] = pooled[g * 128 + t];
    __syncthreads();
    float acc = bc1[t];
    #pragma unroll 8
    for (int k = 0; k < 128; ++k) acc += p[k] * Wc1[k * 256 + t];
    float z = (acc - rmean[t]) * rsqrtf(rvar[t] + 1e-5f) * gamma[t] + beta[t];
    z = fmaxf(z, 0.f);
    r0[t] = z * Wc2[t * 2 + 0];
    r1[t] = z * Wc2[t * 2 + 1];
    __syncthreads();
    for (int s = 128; s > 0; s >>= 1) {
        if (t < s) { r0[t] += r0[t + s]; r1[t] += r1[t + s]; }
        __syncthreads();
    }
    if (t == 0) {
        out[g * 2 + 0] = r0[0] + bc2[0];
        out[g * 2 + 1] = r1[0] + bc2[1];
    }
}

// ---------------- launch ----------------

static inline size_t al256(size_t x) { return (x + 255) & ~size_t(255); }

extern "C" void kernel_launch(void* const* d_in, const int* in_sizes, int n_in,
                              void* d_out, int out_size, void* d_ws, size_t ws_size,
                              hipStream_t stream) {
    const float* x    = (const float*)d_in[0];
    const int*   ei   = (const int*)  d_in[1];
    const int*   batch= (const int*)  d_in[3];
    const float* W0a = (const float*)d_in[4];  const float* b0a = (const float*)d_in[5];
    const float* W0b = (const float*)d_in[6];  const float* b0b = (const float*)d_in[7];
    const float* W1a = (const float*)d_in[8];  const float* b1a = (const float*)d_in[9];
    const float* W1b = (const float*)d_in[10]; const float* b1b = (const float*)d_in[11];
    const float* W2a = (const float*)d_in[12]; const float* b2a = (const float*)d_in[13];
    const float* W2b = (const float*)d_in[14]; const float* b2b = (const float*)d_in[15];
    const float* Wjk = (const float*)d_in[16]; const float* bjk = (const float*)d_in[17];
    const float* Wc1 = (const float*)d_in[18]; const float* bc1 = (const float*)d_in[19];
    const float* gamma=(const float*)d_in[20]; const float* beta= (const float*)d_in[21];
    const float* rmean=(const float*)d_in[22]; const float* rvar= (const float*)d_in[23];
    const float* Wc2 = (const float*)d_in[24]; const float* bc2 = (const float*)d_in[25];
    float* out = (float*)d_out;

    const int N = NN, E = EE, B = BB;

    char* w = (char*)d_ws;
    size_t off = 0;
    int* deg    = (int*)(w + off); off = al256(off + (size_t)N * 4);
    int* rowptr = (int*)(w + off); off = al256(off + (size_t)(N + 1) * 4);
    int* bcur   = (int*)(w + off); off = al256(off + (size_t)NBKT * 4);
    int* colarr = (int*)(w + off); off = al256(off + (size_t)E * 4);
    int* ebuf   = (int*)(w + off); off = al256(off + (size_t)E * 4);
    int* bsum   = (int*)(w + off); off = al256(off + 1024 * 4);
    float* h0   = (float*)(w + off); off = al256(off + (size_t)N * 8 * 4);
    ushort* XB0 = (ushort*)(w + off); off = al256(off + (size_t)N * 128 * 2);
    ushort* XB1 = (ushort*)(w + off); off = al256(off + (size_t)N * 128 * 2);
    ushort* XB2 = (ushort*)(w + off); off = al256(off + (size_t)N * 128 * 2);
    float* pooled = (float*)(w + off); off = al256(off + (size_t)B * 128 * 4);
    ushort* wfH = (ushort*)(w + off); off = al256(off + (size_t)8 * 16384 * 2);
    ushort* wfL = (ushort*)(w + off); off = al256(off + (size_t)8 * 16384 * 2);

    hipMemsetAsync(deg, 0, (size_t)N * 4, stream);
    hipMemsetAsync(pooled, 0, (size_t)B * 128 * 4, stream);

    // pre-split weights (order: W0b, W1a, W1b, W2a, W2b, Wjk0, Wjk1, Wjk2)
    wsplit_all<<<512, 256, 0, stream>>>(W0b, W1a, W1b, W2a, W2b,
                                        Wjk, Wjk + 128 * 128, Wjk + 256 * 128,
                                        wfH, wfL);

    int nb = (N + 1023) / 1024;   // 98

    count_deg<<<(E + 255) / 256, 256, 0, stream>>>(ei, deg, E);
    scan_partial<<<nb, 256, 0, stream>>>(deg, bsum, N);
    scan_bsum<<<1, 256, 0, stream>>>(bsum, nb);
    scan_apply<<<nb, 256, 0, stream>>>(deg, bsum, rowptr, bcur, N, E);
    bin_edges2<<<(E + BIN_CHUNK - 1) / BIN_CHUNK, 256, 0, stream>>>(ei, bcur, ebuf, E);
    distribute<<<NBKT, 256, 0, stream>>>(ebuf, rowptr, colarr, N);

    int gLin = (N + 31) / 32;   // 3125

    // Layer 0: agg7 -> lin7 (bf16 t0 -> XB0) -> mlp0, x1 -> XB1 (bf16)
    agg7<<<(N + 31) / 32, 256, 0, stream>>>(x, rowptr, colarr, h0, N);
    lin7<<<(N + 7) / 8, 256, 0, stream>>>(h0, W0a, b0a, XB0, N);
    mlp_fused<false, false, false, true><<<gLin, 512, 0, stream>>>(
        XB0, rowptr, colarr,
        nullptr, nullptr, nullptr,
        wfH + 0 * 16384, wfL + 0 * 16384, b0b,
        wfH + 5 * 16384, wfL + 5 * 16384, nullptr,
        batch, XB1, pooled, N);

    // Layer 1: bf16 gather XB1 -> MLP -> x2 -> XB2 (bf16)
    mlp_fused<true, true, false, true><<<gLin, 512, 0, stream>>>(
        XB1, rowptr, colarr,
        wfH + 1 * 16384, wfL + 1 * 16384, b1a,
        wfH + 2 * 16384, wfL + 2 * 16384, b1b,
        wfH + 6 * 16384, wfL + 6 * 16384, nullptr,
        batch, XB2, pooled, N);

    // Layer 2: bf16 gather XB2 -> MLP -> jk2 (x3 never materialized)
    mlp_fused<true, true, true, false><<<gLin, 512, 0, stream>>>(
        XB2, rowptr, colarr,
        wfH + 3 * 16384, wfL + 3 * 16384, b2a,
        wfH + 4 * 16384, wfL + 4 * 16384, b2b,
        wfH + 7 * 16384, wfL + 7 * 16384, bjk,
        batch, nullptr, pooled, N);

    classifier<<<B, 256, 0, stream>>>(pooled, Wc1, bc1, gamma, beta,
                                      rmean, rvar, Wc2, bc2, out);
}